// Round 10
// baseline (329.941 us; speedup 1.0000x reference)
//
#include <hip/hip_runtime.h>

#define NEG_SLOPE 0.2f

__device__ __forceinline__ float lrelu(float x) { return x > 0.f ? x : NEG_SLOPE * x; }

// ---------------------------------------------------------------------------
// K1 (layers 1-2): h = X @ W, OUT=128, 128x128 block tile, 8x8 micro-tile.
// 256 threads = 16 col-threads x 16 row-threads; KC=16 (LDS 16 KB).
// Epilogue: H float4x2 store + per-(row,head) logits via 8-lane shfl reduce.
// ---------------------------------------------------------------------------
template<int K>
__global__ __launch_bounds__(256) void gemm_logits128(
    const float* __restrict__ X, const float* __restrict__ W,
    const float* __restrict__ a_s, const float* __restrict__ a_d,
    float* __restrict__ Hout, float* __restrict__ als, float* __restrict__ ald,
    int n)
{
    constexpr int KC = 16;
    __shared__ __align__(16) float Xs[128][KC];
    __shared__ __align__(16) float Ws[KC][128];

    const int tx = (int)threadIdx.x & 15;    // col group (8 cols)
    const int ty = (int)threadIdx.x >> 4;    // row group (8 rows)
    const int r0 = blockIdx.x * 128;

    float4 acc[8][2];
#pragma unroll
    for (int m = 0; m < 8; ++m) {
        acc[m][0] = make_float4(0.f, 0.f, 0.f, 0.f);
        acc[m][1] = make_float4(0.f, 0.f, 0.f, 0.f);
    }

    for (int kc = 0; kc < K; kc += KC) {
        __syncthreads();
        // X tile: 128 rows x 16 k = 512 float4, 2 per thread
#pragma unroll
        for (int it = 0; it < 2; ++it) {
            int i = it * 256 + (int)threadIdx.x;
            int r = i >> 2, kcol = (i & 3) * 4;
            int gr = r0 + r;
            float4 v = make_float4(0.f, 0.f, 0.f, 0.f);
            if (gr < n) v = *(const float4*)(X + (size_t)gr * K + kc + kcol);
            *(float4*)(&Xs[r][kcol]) = v;
        }
        // W chunk: 16 k x 128 cols = 512 float4, 2 per thread
#pragma unroll
        for (int it = 0; it < 2; ++it) {
            int i = it * 256 + (int)threadIdx.x;
            int k = i >> 5, c = (i & 31) * 4;
            *(float4*)(&Ws[k][c]) = *(const float4*)(W + (size_t)(kc + k) * 128 + c);
        }
        __syncthreads();

#pragma unroll
        for (int k4 = 0; k4 < KC / 4; ++k4) {
            float4 xv[8];
#pragma unroll
            for (int m = 0; m < 8; ++m)
                xv[m] = *(const float4*)(&Xs[ty * 8 + m][k4 * 4]);
#pragma unroll
            for (int kk = 0; kk < 4; ++kk) {
                float4 wv0 = *(const float4*)(&Ws[k4 * 4 + kk][tx * 8]);
                float4 wv1 = *(const float4*)(&Ws[k4 * 4 + kk][tx * 8 + 4]);
#pragma unroll
                for (int m = 0; m < 8; ++m) {
                    float xm = ((const float*)&xv[m])[kk];
                    acc[m][0].x = fmaf(xm, wv0.x, acc[m][0].x);
                    acc[m][0].y = fmaf(xm, wv0.y, acc[m][0].y);
                    acc[m][0].z = fmaf(xm, wv0.z, acc[m][0].z);
                    acc[m][0].w = fmaf(xm, wv0.w, acc[m][0].w);
                    acc[m][1].x = fmaf(xm, wv1.x, acc[m][1].x);
                    acc[m][1].y = fmaf(xm, wv1.y, acc[m][1].y);
                    acc[m][1].z = fmaf(xm, wv1.z, acc[m][1].z);
                    acc[m][1].w = fmaf(xm, wv1.w, acc[m][1].w);
                }
            }
        }
    }

    // epilogue: store H and logits (cols tx*8..+8 are inside one head)
    const float4 as0 = *(const float4*)(a_s + tx * 8);
    const float4 as1 = *(const float4*)(a_s + tx * 8 + 4);
    const float4 ad0 = *(const float4*)(a_d + tx * 8);
    const float4 ad1 = *(const float4*)(a_d + tx * 8 + 4);
    const int head = tx >> 3;
#pragma unroll
    for (int m = 0; m < 8; ++m) {
        int gr = r0 + ty * 8 + m;
        float ps = acc[m][0].x * as0.x + acc[m][0].y * as0.y + acc[m][0].z * as0.z + acc[m][0].w * as0.w
                 + acc[m][1].x * as1.x + acc[m][1].y * as1.y + acc[m][1].z * as1.z + acc[m][1].w * as1.w;
        float pd = acc[m][0].x * ad0.x + acc[m][0].y * ad0.y + acc[m][0].z * ad0.z + acc[m][0].w * ad0.w
                 + acc[m][1].x * ad1.x + acc[m][1].y * ad1.y + acc[m][1].z * ad1.z + acc[m][1].w * ad1.w;
        ps += __shfl_xor(ps, 1, 64);
        pd += __shfl_xor(pd, 1, 64);
        ps += __shfl_xor(ps, 2, 64);
        pd += __shfl_xor(pd, 2, 64);
        ps += __shfl_xor(ps, 4, 64);
        pd += __shfl_xor(pd, 4, 64);
        if (gr < n) {
            *(float4*)(Hout + (size_t)gr * 128 + tx * 8)     = acc[m][0];
            *(float4*)(Hout + (size_t)gr * 128 + tx * 8 + 4) = acc[m][1];
            if ((tx & 7) == 0) {
                als[gr * 2 + head] = ps;
                ald[gr * 2 + head] = pd;
            }
        }
    }
}

// ---------------------------------------------------------------------------
// K1 (layer 3): h = X @ W, OUT=32 — R3-style register tile.
// ---------------------------------------------------------------------------
template<int K, int OUT, int F>
__global__ __launch_bounds__(256) void gemm_logits(
    const float* __restrict__ X, const float* __restrict__ W,
    const float* __restrict__ a_s, const float* __restrict__ a_d,
    float* __restrict__ Hout, float* __restrict__ als, float* __restrict__ ald,
    int n)
{
    constexpr int TX = OUT / 4;
    constexpr int TY = 256 / TX;
    constexpr int MR = 8;
    constexpr int BM = TY * MR;
    constexpr int KC = 32;

    __shared__ __align__(16) float Xs[BM][KC];
    __shared__ __align__(16) float Ws[KC][OUT];

    const int tx = (int)threadIdx.x % TX;
    const int ty = (int)threadIdx.x / TX;
    const int r0 = blockIdx.x * BM;

    float4 acc[MR];
#pragma unroll
    for (int m = 0; m < MR; ++m) acc[m] = make_float4(0.f, 0.f, 0.f, 0.f);

    for (int kc = 0; kc < K; kc += KC) {
        __syncthreads();
        constexpr int XV = BM * KC / 4;
#pragma unroll
        for (int i = threadIdx.x; i < XV; i += 256) {
            int f = i * 4;
            int r = f / KC, k = f % KC;
            int gr = r0 + r;
            float4 v = make_float4(0.f, 0.f, 0.f, 0.f);
            if (gr < n) v = *(const float4*)(X + (size_t)gr * K + kc + k);
            *(float4*)(&Xs[r][k]) = v;
        }
        constexpr int WV = KC * OUT / 4;
#pragma unroll
        for (int i = threadIdx.x; i < WV; i += 256) {
            int f = i * 4;
            int k = f / OUT, c = f % OUT;
            *(float4*)(&Ws[k][c]) = *(const float4*)(W + (size_t)(kc + k) * OUT + c);
        }
        __syncthreads();

#pragma unroll
        for (int k4 = 0; k4 < KC; k4 += 4) {
            float4 xv[MR];
#pragma unroll
            for (int m = 0; m < MR; ++m)
                xv[m] = *(const float4*)(&Xs[ty * MR + m][k4]);
#pragma unroll
            for (int kk = 0; kk < 4; ++kk) {
                float4 wv = *(const float4*)(&Ws[k4 + kk][tx * 4]);
#pragma unroll
                for (int m = 0; m < MR; ++m) {
                    float xm = kk == 0 ? xv[m].x : kk == 1 ? xv[m].y : kk == 2 ? xv[m].z : xv[m].w;
                    acc[m].x = fmaf(xm, wv.x, acc[m].x);
                    acc[m].y = fmaf(xm, wv.y, acc[m].y);
                    acc[m].z = fmaf(xm, wv.z, acc[m].z);
                    acc[m].w = fmaf(xm, wv.w, acc[m].w);
                }
            }
        }
    }

    const float4 asv = *(const float4*)(a_s + tx * 4);
    const float4 adv = *(const float4*)(a_d + tx * 4);
    constexpr int UH = F / 4;
    const int head = tx / UH;
#pragma unroll
    for (int m = 0; m < MR; ++m) {
        int gr = r0 + ty * MR + m;
        float ps = acc[m].x * asv.x + acc[m].y * asv.y + acc[m].z * asv.z + acc[m].w * asv.w;
        float pd = acc[m].x * adv.x + acc[m].y * adv.y + acc[m].z * adv.z + acc[m].w * adv.w;
#pragma unroll
        for (int off = UH / 2; off > 0; off >>= 1) {
            ps += __shfl_xor(ps, off, 64);
            pd += __shfl_xor(pd, off, 64);
        }
        if (gr < n) {
            *(float4*)(Hout + (size_t)gr * OUT + tx * 4) = acc[m];
            if ((tx % UH) == 0) {
                als[gr * 2 + head] = ps;
                ald[gr * 2 + head] = pd;
            }
        }
    }
}

// ---------------------------------------------------------------------------
// CSR build. Parallel 3-kernel scan.
// ---------------------------------------------------------------------------
#define SCAN_TILE 1024

__global__ __launch_bounds__(256) void k_hist(const int* __restrict__ dst,
                                              int* __restrict__ deg, int E) {
    int e = blockIdx.x * 256 + threadIdx.x;
    if (e < E) atomicAdd(&deg[dst[e]], 1);
}

__global__ __launch_bounds__(256) void k_scan1(const int* __restrict__ deg,
                                               int* __restrict__ bsum, int N) {
    __shared__ int sm[256];
    int base = blockIdx.x * SCAN_TILE;
    int t = threadIdx.x;
    int s = 0;
#pragma unroll
    for (int j = 0; j < SCAN_TILE / 256; ++j) {
        int i = base + j * 256 + t;
        if (i < N) s += deg[i];
    }
    sm[t] = s;
    __syncthreads();
    for (int off = 128; off > 0; off >>= 1) {
        if (t < off) sm[t] += sm[t + off];
        __syncthreads();
    }
    if (t == 0) bsum[blockIdx.x] = sm[0];
}

__global__ __launch_bounds__(256) void k_scan2(const int* __restrict__ bsum,
                                               int* __restrict__ boff,
                                               int* __restrict__ rowptr,
                                               int nb, int N) {
    __shared__ int sm[256];
    int t = threadIdx.x;
    int v = (t < nb) ? bsum[t] : 0;
    sm[t] = v;
    __syncthreads();
    for (int off = 1; off < 256; off <<= 1) {
        int u = (t >= off) ? sm[t - off] : 0;
        __syncthreads();
        sm[t] += u;
        __syncthreads();
    }
    if (t < nb) boff[t] = sm[t] - v;
    if (t == 255) rowptr[N] = sm[255];
}

__global__ __launch_bounds__(256) void k_scan3(const int* __restrict__ deg,
                                               const int* __restrict__ boff,
                                               int* __restrict__ rowptr,
                                               int* __restrict__ cursor, int N) {
    __shared__ int sm[256];
    int base = blockIdx.x * SCAN_TILE;
    int t = threadIdx.x;
    int i0 = base + t * 4;
    int d0 = 0, d1 = 0, d2 = 0, d3 = 0;
    if (i0 + 3 < N) {
        int4 v = *(const int4*)(deg + i0);
        d0 = v.x; d1 = v.y; d2 = v.z; d3 = v.w;
    } else {
        if (i0 + 0 < N) d0 = deg[i0 + 0];
        if (i0 + 1 < N) d1 = deg[i0 + 1];
        if (i0 + 2 < N) d2 = deg[i0 + 2];
        if (i0 + 3 < N) d3 = deg[i0 + 3];
    }
    int tsum = d0 + d1 + d2 + d3;
    sm[t] = tsum;
    __syncthreads();
    for (int off = 1; off < 256; off <<= 1) {
        int u = (t >= off) ? sm[t - off] : 0;
        __syncthreads();
        sm[t] += u;
        __syncthreads();
    }
    int run = boff[blockIdx.x] + sm[t] - tsum;
    if (i0 + 0 < N) { rowptr[i0 + 0] = run; cursor[i0 + 0] = run; run += d0; }
    if (i0 + 1 < N) { rowptr[i0 + 1] = run; cursor[i0 + 1] = run; run += d1; }
    if (i0 + 2 < N) { rowptr[i0 + 2] = run; cursor[i0 + 2] = run; run += d2; }
    if (i0 + 3 < N) { rowptr[i0 + 3] = run; cursor[i0 + 3] = run; run += d3; }
}

__global__ __launch_bounds__(256) void k_scatter(const int* __restrict__ src,
                                                 const int* __restrict__ dst,
                                                 int* __restrict__ cursor,
                                                 int* __restrict__ esorted, int E) {
    int e = blockIdx.x * 256 + threadIdx.x;
    if (e >= E) return;
    int p = atomicAdd(&cursor[dst[e]], 1);
    esorted[p] = src[e];
}

// ---------------------------------------------------------------------------
// B: gather-aggregate, layers 1-2, fused edge weights (R9, unchanged).
// ---------------------------------------------------------------------------
__global__ __launch_bounds__(256) void gat_gather128(
    const int* __restrict__ rowptr, const int* __restrict__ esorted,
    const float* __restrict__ als, const float* __restrict__ ald,
    const float* __restrict__ H, const float* __restrict__ bias,
    float* __restrict__ out, int N)
{
    const int node = blockIdx.x * 8 + ((int)threadIdx.x >> 5);
    const int lane = (int)threadIdx.x & 31;
    if (node >= N) return;
    const int head = lane >> 4;

    const float2 alsv = *(const float2*)(als + node * 2);
    const float2 aldv = *(const float2*)(ald + node * 2);
    const float aldh = head ? aldv.y : aldv.x;
    const float alsh = head ? alsv.y : alsv.x;
    const float ws = expf(lrelu(alsh + aldh));

    const float4 hown = *(const float4*)(H + (size_t)node * 128 + lane * 4);
    float4 accA = make_float4(ws * hown.x, ws * hown.y, ws * hown.z, ws * hown.w);
    float4 accB = make_float4(0.f, 0.f, 0.f, 0.f);
    float4 accC = make_float4(0.f, 0.f, 0.f, 0.f);
    float4 accD = make_float4(0.f, 0.f, 0.f, 0.f);
    float den = ws;

    int p = rowptr[node];
    const int end = rowptr[node + 1];
    for (; p + 4 <= end; p += 4) {
        int s0 = esorted[p], s1 = esorted[p + 1], s2 = esorted[p + 2], s3 = esorted[p + 3];
        float2 a0 = *(const float2*)(als + s0 * 2);
        float2 a1 = *(const float2*)(als + s1 * 2);
        float2 a2 = *(const float2*)(als + s2 * 2);
        float2 a3 = *(const float2*)(als + s3 * 2);
        float4 h0 = *(const float4*)(H + (size_t)s0 * 128 + lane * 4);
        float4 h1 = *(const float4*)(H + (size_t)s1 * 128 + lane * 4);
        float4 h2 = *(const float4*)(H + (size_t)s2 * 128 + lane * 4);
        float4 h3 = *(const float4*)(H + (size_t)s3 * 128 + lane * 4);
        float w0 = expf(lrelu((head ? a0.y : a0.x) + aldh));
        float w1 = expf(lrelu((head ? a1.y : a1.x) + aldh));
        float w2 = expf(lrelu((head ? a2.y : a2.x) + aldh));
        float w3 = expf(lrelu((head ? a3.y : a3.x) + aldh));
        accA.x = fmaf(w0, h0.x, accA.x); accA.y = fmaf(w0, h0.y, accA.y);
        accA.z = fmaf(w0, h0.z, accA.z); accA.w = fmaf(w0, h0.w, accA.w);
        accB.x = fmaf(w1, h1.x, accB.x); accB.y = fmaf(w1, h1.y, accB.y);
        accB.z = fmaf(w1, h1.z, accB.z); accB.w = fmaf(w1, h1.w, accB.w);
        accC.x = fmaf(w2, h2.x, accC.x); accC.y = fmaf(w2, h2.y, accC.y);
        accC.z = fmaf(w2, h2.z, accC.z); accC.w = fmaf(w2, h2.w, accC.w);
        accD.x = fmaf(w3, h3.x, accD.x); accD.y = fmaf(w3, h3.y, accD.y);
        accD.z = fmaf(w3, h3.z, accD.z); accD.w = fmaf(w3, h3.w, accD.w);
        den += (w0 + w1) + (w2 + w3);
    }
    for (; p < end; ++p) {
        int s0 = esorted[p];
        float2 a0 = *(const float2*)(als + s0 * 2);
        float4 h0 = *(const float4*)(H + (size_t)s0 * 128 + lane * 4);
        float w0 = expf(lrelu((head ? a0.y : a0.x) + aldh));
        accA.x = fmaf(w0, h0.x, accA.x); accA.y = fmaf(w0, h0.y, accA.y);
        accA.z = fmaf(w0, h0.z, accA.z); accA.w = fmaf(w0, h0.w, accA.w);
        den += w0;
    }

    const float r = 1.f / (den + 1e-16f);
    const float4 bv = *(const float4*)(bias + lane * 4);
    float4 v;
    v.x = (accA.x + accB.x + accC.x + accD.x) * r + bv.x;
    v.y = (accA.y + accB.y + accC.y + accD.y) * r + bv.y;
    v.z = (accA.z + accB.z + accC.z + accD.z) * r + bv.z;
    v.w = (accA.w + accB.w + accC.w + accD.w) * r + bv.w;
    v.x = v.x > 0.f ? v.x : 0.f;
    v.y = v.y > 0.f ? v.y : 0.f;
    v.z = v.z > 0.f ? v.z : 0.f;
    v.w = v.w > 0.f ? v.w : 0.f;
    *(float4*)(out + (size_t)node * 128 + lane * 4) = v;
}

// ---------------------------------------------------------------------------
// C: layer-3 gather (fused weights) + fused mean/bias/softmax (R9, unchanged).
// ---------------------------------------------------------------------------
__global__ __launch_bounds__(256) void gat_gather_final(
    const int* __restrict__ rowptr, const int* __restrict__ esorted,
    const float* __restrict__ als, const float* __restrict__ ald,
    const float* __restrict__ H3, const float* __restrict__ b3,
    float* __restrict__ out, int N)
{
    const int node = blockIdx.x * 32 + ((int)threadIdx.x >> 3);
    const int lane = (int)threadIdx.x & 7;
    if (node >= N) return;
    const int head = lane >> 2;
    const int sub = lane & 3;

    const float2 alsv = *(const float2*)(als + node * 2);
    const float2 aldv = *(const float2*)(ald + node * 2);
    const float aldh = head ? aldv.y : aldv.x;
    const float alsh = head ? alsv.y : alsv.x;
    const float ws = expf(lrelu(alsh + aldh));

    const float4 hown = *(const float4*)(H3 + (size_t)node * 32 + head * 16 + sub * 4);
    float4 accA = make_float4(ws * hown.x, ws * hown.y, ws * hown.z, ws * hown.w);
    float4 accB = make_float4(0.f, 0.f, 0.f, 0.f);
    float den = ws;

    int p = rowptr[node];
    const int end = rowptr[node + 1];
    for (; p + 2 <= end; p += 2) {
        int s0 = esorted[p], s1 = esorted[p + 1];
        float2 a0 = *(const float2*)(als + s0 * 2);
        float2 a1 = *(const float2*)(als + s1 * 2);
        float4 h0 = *(const float4*)(H3 + (size_t)s0 * 32 + head * 16 + sub * 4);
        float4 h1 = *(const float4*)(H3 + (size_t)s1 * 32 + head * 16 + sub * 4);
        float w0 = expf(lrelu((head ? a0.y : a0.x) + aldh));
        float w1 = expf(lrelu((head ? a1.y : a1.x) + aldh));
        accA.x = fmaf(w0, h0.x, accA.x); accA.y = fmaf(w0, h0.y, accA.y);
        accA.z = fmaf(w0, h0.z, accA.z); accA.w = fmaf(w0, h0.w, accA.w);
        accB.x = fmaf(w1, h1.x, accB.x); accB.y = fmaf(w1, h1.y, accB.y);
        accB.z = fmaf(w1, h1.z, accB.z); accB.w = fmaf(w1, h1.w, accB.w);
        den += w0 + w1;
    }
    if (p < end) {
        int s0 = esorted[p];
        float2 a0 = *(const float2*)(als + s0 * 2);
        float4 h0 = *(const float4*)(H3 + (size_t)s0 * 32 + head * 16 + sub * 4);
        float w0 = expf(lrelu((head ? a0.y : a0.x) + aldh));
        accA.x = fmaf(w0, h0.x, accA.x); accA.y = fmaf(w0, h0.y, accA.y);
        accA.z = fmaf(w0, h0.z, accA.z); accA.w = fmaf(w0, h0.w, accA.w);
        den += w0;
    }

    const float r = 1.f / (den + 1e-16f);
    float4 a;
    a.x = (accA.x + accB.x) * r;
    a.y = (accA.y + accB.y) * r;
    a.z = (accA.z + accB.z) * r;
    a.w = (accA.w + accB.w) * r;
    float4 ap;
    ap.x = __shfl_xor(a.x, 4, 64);
    ap.y = __shfl_xor(a.y, 4, 64);
    ap.z = __shfl_xor(a.z, 4, 64);
    ap.w = __shfl_xor(a.w, 4, 64);
    const float4 bv = *(const float4*)(b3 + sub * 4);
    float4 v;
    v.x = 0.5f * (a.x + ap.x) + bv.x;
    v.y = 0.5f * (a.y + ap.y) + bv.y;
    v.z = 0.5f * (a.z + ap.z) + bv.z;
    v.w = 0.5f * (a.w + ap.w) + bv.w;
    float mx = fmaxf(fmaxf(v.x, v.y), fmaxf(v.z, v.w));
    mx = fmaxf(mx, __shfl_xor(mx, 1, 64));
    mx = fmaxf(mx, __shfl_xor(mx, 2, 64));
    float4 ex;
    ex.x = expf(v.x - mx);
    ex.y = expf(v.y - mx);
    ex.z = expf(v.z - mx);
    ex.w = expf(v.w - mx);
    float sum = ex.x + ex.y + ex.z + ex.w;
    sum += __shfl_xor(sum, 1, 64);
    sum += __shfl_xor(sum, 2, 64);
    const float rs = 1.f / sum;
    if (head == 0) {
        float4 o = make_float4(ex.x * rs, ex.y * rs, ex.z * rs, ex.w * rs);
        *(float4*)(out + (size_t)node * 16 + sub * 4) = o;
    }
}

// ---------------------------------------------------------------------------
extern "C" void kernel_launch(void* const* d_in, const int* in_sizes, int n_in,
                              void* d_out, int out_size, void* d_ws, size_t ws_size,
                              hipStream_t stream)
{
    const float* feat = (const float*)d_in[0];
    const int*   ei   = (const int*)d_in[1];
    const float* W1 = (const float*)d_in[2];
    const float* a1s = (const float*)d_in[3];
    const float* a1d = (const float*)d_in[4];
    const float* b1 = (const float*)d_in[5];
    const float* W2 = (const float*)d_in[6];
    const float* a2s = (const float*)d_in[7];
    const float* a2d = (const float*)d_in[8];
    const float* b2 = (const float*)d_in[9];
    const float* W3 = (const float*)d_in[10];
    const float* a3s = (const float*)d_in[11];
    const float* a3d = (const float*)d_in[12];
    const float* b3 = (const float*)d_in[13];

    const int N = in_sizes[0] / 64;
    const int E = in_sizes[1] / 2;
    const int* src = ei;
    const int* dst = ei + E;
    const int n2 = N * 2;
    const int nb = (N + SCAN_TILE - 1) / SCAN_TILE;

    // workspace layout
    float* bufA  = (float*)d_ws;                    // N*128 (H)
    float* bufB  = bufA + (size_t)N * 128;          // N*128 (x / out)
    float* als   = bufB + (size_t)N * 128;          // n2
    float* ald   = als + (size_t)n2;                // n2
    int* deg     = (int*)(ald + (size_t)n2);        // N
    int* rowptr  = deg + N;                         // N+1
    int* cursor  = rowptr + (N + 1);                // N
    int* bsum    = cursor + N;                      // nb
    int* boff    = bsum + nb;                       // nb
    int* esorted = boff + nb;                       // E

    dim3 blk(256);
    const int gE = (E + 255) / 256;

    // --- build CSR by dst (once; shared by all 3 layers) ---
    hipMemsetAsync(deg, 0, (size_t)N * sizeof(int), stream);
    k_hist<<<gE, blk, 0, stream>>>(dst, deg, E);
    k_scan1<<<nb, blk, 0, stream>>>(deg, bsum, N);
    k_scan2<<<1, blk, 0, stream>>>(bsum, boff, rowptr, nb, N);
    k_scan3<<<nb, blk, 0, stream>>>(deg, boff, rowptr, cursor, N);
    k_scatter<<<gE, blk, 0, stream>>>(src, dst, cursor, esorted, E);

    // --- layer 1 (K=64) ---
    gemm_logits128<64><<<(N + 127) / 128, blk, 0, stream>>>(feat, W1, a1s, a1d, bufA, als, ald, N);
    gat_gather128<<<(N + 7) / 8, blk, 0, stream>>>(rowptr, esorted, als, ald, bufA, b1, bufB, N);

    // --- layer 2 (K=128) ---
    gemm_logits128<128><<<(N + 127) / 128, blk, 0, stream>>>(bufB, W2, a2s, a2d, bufA, als, ald, N);
    gat_gather128<<<(N + 7) / 8, blk, 0, stream>>>(rowptr, esorted, als, ald, bufA, b2, bufB, N);

    // --- layer 3 (K=128, OUT=32) ---
    gemm_logits<128, 32, 16><<<(N + 255) / 256, blk, 0, stream>>>(bufB, W3, a3s, a3d, bufA, als, ald, N);
    gat_gather_final<<<(N + 31) / 32, blk, 0, stream>>>(rowptr, esorted, als, ald, bufA, b3, (float*)d_out, N);
}

// Round 11
// 313.091 us; speedup vs baseline: 1.0538x; 1.0538x over previous
//
#include <hip/hip_runtime.h>

#define NEG_SLOPE 0.2f

__device__ __forceinline__ float lrelu(float x) { return x > 0.f ? x : NEG_SLOPE * x; }

// ---------------------------------------------------------------------------
// K1: h = X @ W (register-tiled, R3 tile) + per-(node,head) logits.
// HSPLIT=true (layers 1-2): H written HEAD-MAJOR Hh[2][n][64].
// als/ald written head-major: als[head*n + node].
// ---------------------------------------------------------------------------
template<int K, int OUT, int F, bool HSPLIT>
__global__ __launch_bounds__(256) void gemm_logits(
    const float* __restrict__ X, const float* __restrict__ W,
    const float* __restrict__ a_s, const float* __restrict__ a_d,
    float* __restrict__ Hout, float* __restrict__ als, float* __restrict__ ald,
    int n)
{
    constexpr int TX = OUT / 4;
    constexpr int TY = 256 / TX;
    constexpr int MR = 8;
    constexpr int BM = TY * MR;
    constexpr int KC = 32;

    __shared__ __align__(16) float Xs[BM][KC];
    __shared__ __align__(16) float Ws[KC][OUT];

    const int tx = (int)threadIdx.x % TX;
    const int ty = (int)threadIdx.x / TX;
    const int r0 = blockIdx.x * BM;

    float4 acc[MR];
#pragma unroll
    for (int m = 0; m < MR; ++m) acc[m] = make_float4(0.f, 0.f, 0.f, 0.f);

    for (int kc = 0; kc < K; kc += KC) {
        __syncthreads();
        constexpr int XV = BM * KC / 4;
#pragma unroll
        for (int i = threadIdx.x; i < XV; i += 256) {
            int f = i * 4;
            int r = f / KC, k = f % KC;
            int gr = r0 + r;
            float4 v = make_float4(0.f, 0.f, 0.f, 0.f);
            if (gr < n) v = *(const float4*)(X + (size_t)gr * K + kc + k);
            *(float4*)(&Xs[r][k]) = v;
        }
        constexpr int WV = KC * OUT / 4;
#pragma unroll
        for (int i = threadIdx.x; i < WV; i += 256) {
            int f = i * 4;
            int k = f / OUT, c = f % OUT;
            *(float4*)(&Ws[k][c]) = *(const float4*)(W + (size_t)(kc + k) * OUT + c);
        }
        __syncthreads();

#pragma unroll
        for (int k4 = 0; k4 < KC; k4 += 4) {
            float4 xv[MR];
#pragma unroll
            for (int m = 0; m < MR; ++m)
                xv[m] = *(const float4*)(&Xs[ty * MR + m][k4]);
#pragma unroll
            for (int kk = 0; kk < 4; ++kk) {
                float4 wv = *(const float4*)(&Ws[k4 + kk][tx * 4]);
#pragma unroll
                for (int m = 0; m < MR; ++m) {
                    float xm = kk == 0 ? xv[m].x : kk == 1 ? xv[m].y : kk == 2 ? xv[m].z : xv[m].w;
                    acc[m].x = fmaf(xm, wv.x, acc[m].x);
                    acc[m].y = fmaf(xm, wv.y, acc[m].y);
                    acc[m].z = fmaf(xm, wv.z, acc[m].z);
                    acc[m].w = fmaf(xm, wv.w, acc[m].w);
                }
            }
        }
    }

    const float4 asv = *(const float4*)(a_s + tx * 4);
    const float4 adv = *(const float4*)(a_d + tx * 4);
    constexpr int UH = F / 4;                 // tx-lanes per head
    const int head = tx / UH;
#pragma unroll
    for (int m = 0; m < MR; ++m) {
        int gr = r0 + ty * MR + m;
        float ps = acc[m].x * asv.x + acc[m].y * asv.y + acc[m].z * asv.z + acc[m].w * asv.w;
        float pd = acc[m].x * adv.x + acc[m].y * adv.y + acc[m].z * adv.z + acc[m].w * adv.w;
#pragma unroll
        for (int off = UH / 2; off > 0; off >>= 1) {
            ps += __shfl_xor(ps, off, 64);
            pd += __shfl_xor(pd, off, 64);
        }
        if (gr < n) {
            if (HSPLIT) {
                // head-major: Hh[head][gr][ (tx%UH)*4 .. ]
                *(float4*)(Hout + ((size_t)head * n + gr) * F + (tx % UH) * 4) = acc[m];
            } else {
                *(float4*)(Hout + (size_t)gr * OUT + tx * 4) = acc[m];
            }
            if ((tx % UH) == 0) {
                als[(size_t)head * n + gr] = ps;
                ald[(size_t)head * n + gr] = pd;
            }
        }
    }
}

// ---------------------------------------------------------------------------
// CSR build. hist -> per-tile sums -> merged scan (each block re-scans the
// <=256 tile sums locally) -> scatter.
// ---------------------------------------------------------------------------
#define SCAN_TILE 1024

__global__ __launch_bounds__(256) void k_hist(const int* __restrict__ dst,
                                              int* __restrict__ deg, int E) {
    int e = blockIdx.x * 256 + threadIdx.x;
    if (e < E) atomicAdd(&deg[dst[e]], 1);
}

__global__ __launch_bounds__(256) void k_scan1(const int* __restrict__ deg,
                                               int* __restrict__ bsum, int N) {
    __shared__ int sm[256];
    int base = blockIdx.x * SCAN_TILE;
    int t = threadIdx.x;
    int s = 0;
#pragma unroll
    for (int j = 0; j < SCAN_TILE / 256; ++j) {
        int i = base + j * 256 + t;
        if (i < N) s += deg[i];
    }
    sm[t] = s;
    __syncthreads();
    for (int off = 128; off > 0; off >>= 1) {
        if (t < off) sm[t] += sm[t + off];
        __syncthreads();
    }
    if (t == 0) bsum[blockIdx.x] = sm[0];
}

// merged: each block computes the global tile-prefix itself, then its local
// exclusive scan; writes rowptr & cursor (+ rowptr[N] from block 0).
__global__ __launch_bounds__(256) void k_scan3(const int* __restrict__ deg,
                                               const int* __restrict__ bsum,
                                               int* __restrict__ rowptr,
                                               int* __restrict__ cursor,
                                               int nb, int N) {
    __shared__ int sm[256];
    __shared__ int sme[256];
    int t = threadIdx.x;
    // block-prefix over tile sums
    int v = (t < nb) ? bsum[t] : 0;
    sm[t] = v;
    __syncthreads();
    for (int off = 1; off < 256; off <<= 1) {
        int u = (t >= off) ? sm[t - off] : 0;
        __syncthreads();
        sm[t] += u;
        __syncthreads();
    }
    sme[t] = sm[t] - v;              // exclusive
    if (blockIdx.x == 0 && t == 255) rowptr[N] = sm[255];
    __syncthreads();
    const int boffv = sme[blockIdx.x];

    // local scan of this tile
    int base = blockIdx.x * SCAN_TILE;
    int i0 = base + t * 4;
    int d0 = 0, d1 = 0, d2 = 0, d3 = 0;
    if (i0 + 3 < N) {
        int4 dv = *(const int4*)(deg + i0);
        d0 = dv.x; d1 = dv.y; d2 = dv.z; d3 = dv.w;
    } else {
        if (i0 + 0 < N) d0 = deg[i0 + 0];
        if (i0 + 1 < N) d1 = deg[i0 + 1];
        if (i0 + 2 < N) d2 = deg[i0 + 2];
        if (i0 + 3 < N) d3 = deg[i0 + 3];
    }
    int tsum = d0 + d1 + d2 + d3;
    __syncthreads();
    sm[t] = tsum;
    __syncthreads();
    for (int off = 1; off < 256; off <<= 1) {
        int u = (t >= off) ? sm[t - off] : 0;
        __syncthreads();
        sm[t] += u;
        __syncthreads();
    }
    int run = boffv + sm[t] - tsum;
    if (i0 + 0 < N) { rowptr[i0 + 0] = run; cursor[i0 + 0] = run; run += d0; }
    if (i0 + 1 < N) { rowptr[i0 + 1] = run; cursor[i0 + 1] = run; run += d1; }
    if (i0 + 2 < N) { rowptr[i0 + 2] = run; cursor[i0 + 2] = run; run += d2; }
    if (i0 + 3 < N) { rowptr[i0 + 3] = run; cursor[i0 + 3] = run; run += d3; }
}

__global__ __launch_bounds__(256) void k_scatter(const int* __restrict__ src,
                                                 const int* __restrict__ dst,
                                                 int* __restrict__ cursor,
                                                 int* __restrict__ esorted, int E) {
    int e = blockIdx.x * 256 + threadIdx.x;
    if (e >= E) return;
    int p = atomicAdd(&cursor[dst[e]], 1);
    esorted[p] = src[e];
}

// ---------------------------------------------------------------------------
// B: head-phased gather, layers 1-2. Grid = two contiguous halves: first
// nblk blocks do head 0 (12.8 MB table), second half head 1 -> per-XCD L2
// working set halves. 16 lanes per (node,head); per edge: uniform esorted +
// uniform als scalar + one coalesced 256 B Hh row; 4-way unroll.
// ---------------------------------------------------------------------------
__global__ __launch_bounds__(256) void gat_gather_head(
    const int* __restrict__ rowptr, const int* __restrict__ esorted,
    const float* __restrict__ als, const float* __restrict__ ald,
    const float* __restrict__ Hh, const float* __restrict__ bias,
    float* __restrict__ out, int N, int nblk)
{
    const int head = (blockIdx.x >= nblk) ? 1 : 0;
    const int nodeblk = blockIdx.x - head * nblk;
    const int node = nodeblk * 16 + ((int)threadIdx.x >> 4);
    const int lane = (int)threadIdx.x & 15;
    if (node >= N) return;

    const float* __restrict__ alsh = als + (size_t)head * N;
    const float aldh = ald[(size_t)head * N + node];
    const float* __restrict__ Ht = Hh + (size_t)head * N * 64;

    const float ws = expf(lrelu(alsh[node] + aldh));
    const float4 hown = *(const float4*)(Ht + (size_t)node * 64 + lane * 4);
    float4 accA = make_float4(ws * hown.x, ws * hown.y, ws * hown.z, ws * hown.w);
    float4 accB = make_float4(0.f, 0.f, 0.f, 0.f);
    float4 accC = make_float4(0.f, 0.f, 0.f, 0.f);
    float4 accD = make_float4(0.f, 0.f, 0.f, 0.f);
    float den = ws;

    int p = rowptr[node];
    const int end = rowptr[node + 1];
    for (; p + 4 <= end; p += 4) {
        int s0 = esorted[p], s1 = esorted[p + 1], s2 = esorted[p + 2], s3 = esorted[p + 3];
        float l0 = alsh[s0], l1 = alsh[s1], l2 = alsh[s2], l3 = alsh[s3];
        float4 h0 = *(const float4*)(Ht + (size_t)s0 * 64 + lane * 4);
        float4 h1 = *(const float4*)(Ht + (size_t)s1 * 64 + lane * 4);
        float4 h2 = *(const float4*)(Ht + (size_t)s2 * 64 + lane * 4);
        float4 h3 = *(const float4*)(Ht + (size_t)s3 * 64 + lane * 4);
        float w0 = expf(lrelu(l0 + aldh));
        float w1 = expf(lrelu(l1 + aldh));
        float w2 = expf(lrelu(l2 + aldh));
        float w3 = expf(lrelu(l3 + aldh));
        accA.x = fmaf(w0, h0.x, accA.x); accA.y = fmaf(w0, h0.y, accA.y);
        accA.z = fmaf(w0, h0.z, accA.z); accA.w = fmaf(w0, h0.w, accA.w);
        accB.x = fmaf(w1, h1.x, accB.x); accB.y = fmaf(w1, h1.y, accB.y);
        accB.z = fmaf(w1, h1.z, accB.z); accB.w = fmaf(w1, h1.w, accB.w);
        accC.x = fmaf(w2, h2.x, accC.x); accC.y = fmaf(w2, h2.y, accC.y);
        accC.z = fmaf(w2, h2.z, accC.z); accC.w = fmaf(w2, h2.w, accC.w);
        accD.x = fmaf(w3, h3.x, accD.x); accD.y = fmaf(w3, h3.y, accD.y);
        accD.z = fmaf(w3, h3.z, accD.z); accD.w = fmaf(w3, h3.w, accD.w);
        den += (w0 + w1) + (w2 + w3);
    }
    for (; p < end; ++p) {
        int s0 = esorted[p];
        float4 h0 = *(const float4*)(Ht + (size_t)s0 * 64 + lane * 4);
        float w0 = expf(lrelu(alsh[s0] + aldh));
        accA.x = fmaf(w0, h0.x, accA.x); accA.y = fmaf(w0, h0.y, accA.y);
        accA.z = fmaf(w0, h0.z, accA.z); accA.w = fmaf(w0, h0.w, accA.w);
        den += w0;
    }

    const float r = 1.f / (den + 1e-16f);
    const float4 bv = *(const float4*)(bias + head * 64 + lane * 4);
    float4 v;
    v.x = (accA.x + accB.x + accC.x + accD.x) * r + bv.x;
    v.y = (accA.y + accB.y + accC.y + accD.y) * r + bv.y;
    v.z = (accA.z + accB.z + accC.z + accD.z) * r + bv.z;
    v.w = (accA.w + accB.w + accC.w + accD.w) * r + bv.w;
    v.x = v.x > 0.f ? v.x : 0.f;
    v.y = v.y > 0.f ? v.y : 0.f;
    v.z = v.z > 0.f ? v.z : 0.f;
    v.w = v.w > 0.f ? v.w : 0.f;
    *(float4*)(out + (size_t)node * 128 + head * 64 + lane * 4) = v;
}

// ---------------------------------------------------------------------------
// C: layer-3 gather (fused weights) + fused mean/bias/softmax.
// 8 lanes per node; als/ald head-major.
// ---------------------------------------------------------------------------
__global__ __launch_bounds__(256) void gat_gather_final(
    const int* __restrict__ rowptr, const int* __restrict__ esorted,
    const float* __restrict__ als, const float* __restrict__ ald,
    const float* __restrict__ H3, const float* __restrict__ b3,
    float* __restrict__ out, int N)
{
    const int node = blockIdx.x * 32 + ((int)threadIdx.x >> 3);
    const int lane = (int)threadIdx.x & 7;
    if (node >= N) return;
    const int head = lane >> 2;
    const int sub = lane & 3;

    const float* __restrict__ alsh = als + (size_t)head * N;
    const float aldh = ald[(size_t)head * N + node];
    const float ws = expf(lrelu(alsh[node] + aldh));

    const float4 hown = *(const float4*)(H3 + (size_t)node * 32 + head * 16 + sub * 4);
    float4 accA = make_float4(ws * hown.x, ws * hown.y, ws * hown.z, ws * hown.w);
    float4 accB = make_float4(0.f, 0.f, 0.f, 0.f);
    float den = ws;

    int p = rowptr[node];
    const int end = rowptr[node + 1];
    for (; p + 2 <= end; p += 2) {
        int s0 = esorted[p], s1 = esorted[p + 1];
        float l0 = alsh[s0], l1 = alsh[s1];
        float4 h0 = *(const float4*)(H3 + (size_t)s0 * 32 + head * 16 + sub * 4);
        float4 h1 = *(const float4*)(H3 + (size_t)s1 * 32 + head * 16 + sub * 4);
        float w0 = expf(lrelu(l0 + aldh));
        float w1 = expf(lrelu(l1 + aldh));
        accA.x = fmaf(w0, h0.x, accA.x); accA.y = fmaf(w0, h0.y, accA.y);
        accA.z = fmaf(w0, h0.z, accA.z); accA.w = fmaf(w0, h0.w, accA.w);
        accB.x = fmaf(w1, h1.x, accB.x); accB.y = fmaf(w1, h1.y, accB.y);
        accB.z = fmaf(w1, h1.z, accB.z); accB.w = fmaf(w1, h1.w, accB.w);
        den += w0 + w1;
    }
    if (p < end) {
        int s0 = esorted[p];
        float4 h0 = *(const float4*)(H3 + (size_t)s0 * 32 + head * 16 + sub * 4);
        float w0 = expf(lrelu(alsh[s0] + aldh));
        accA.x = fmaf(w0, h0.x, accA.x); accA.y = fmaf(w0, h0.y, accA.y);
        accA.z = fmaf(w0, h0.z, accA.z); accA.w = fmaf(w0, h0.w, accA.w);
        den += w0;
    }

    const float r = 1.f / (den + 1e-16f);
    float4 a;
    a.x = (accA.x + accB.x) * r;
    a.y = (accA.y + accB.y) * r;
    a.z = (accA.z + accB.z) * r;
    a.w = (accA.w + accB.w) * r;
    float4 ap;
    ap.x = __shfl_xor(a.x, 4, 64);
    ap.y = __shfl_xor(a.y, 4, 64);
    ap.z = __shfl_xor(a.z, 4, 64);
    ap.w = __shfl_xor(a.w, 4, 64);
    const float4 bv = *(const float4*)(b3 + sub * 4);
    float4 v;
    v.x = 0.5f * (a.x + ap.x) + bv.x;
    v.y = 0.5f * (a.y + ap.y) + bv.y;
    v.z = 0.5f * (a.z + ap.z) + bv.z;
    v.w = 0.5f * (a.w + ap.w) + bv.w;
    float mx = fmaxf(fmaxf(v.x, v.y), fmaxf(v.z, v.w));
    mx = fmaxf(mx, __shfl_xor(mx, 1, 64));
    mx = fmaxf(mx, __shfl_xor(mx, 2, 64));
    float4 ex;
    ex.x = expf(v.x - mx);
    ex.y = expf(v.y - mx);
    ex.z = expf(v.z - mx);
    ex.w = expf(v.w - mx);
    float sum = ex.x + ex.y + ex.z + ex.w;
    sum += __shfl_xor(sum, 1, 64);
    sum += __shfl_xor(sum, 2, 64);
    const float rs = 1.f / sum;
    if (head == 0) {
        float4 o = make_float4(ex.x * rs, ex.y * rs, ex.z * rs, ex.w * rs);
        *(float4*)(out + (size_t)node * 16 + sub * 4) = o;
    }
}

// ---------------------------------------------------------------------------
extern "C" void kernel_launch(void* const* d_in, const int* in_sizes, int n_in,
                              void* d_out, int out_size, void* d_ws, size_t ws_size,
                              hipStream_t stream)
{
    const float* feat = (const float*)d_in[0];
    const int*   ei   = (const int*)d_in[1];
    const float* W1 = (const float*)d_in[2];
    const float* a1s = (const float*)d_in[3];
    const float* a1d = (const float*)d_in[4];
    const float* b1 = (const float*)d_in[5];
    const float* W2 = (const float*)d_in[6];
    const float* a2s = (const float*)d_in[7];
    const float* a2d = (const float*)d_in[8];
    const float* b2 = (const float*)d_in[9];
    const float* W3 = (const float*)d_in[10];
    const float* a3s = (const float*)d_in[11];
    const float* a3d = (const float*)d_in[12];
    const float* b3 = (const float*)d_in[13];

    const int N = in_sizes[0] / 64;
    const int E = in_sizes[1] / 2;
    const int* src = ei;
    const int* dst = ei + E;
    const int n2 = N * 2;
    const int nb = (N + SCAN_TILE - 1) / SCAN_TILE;

    // workspace layout
    float* bufA  = (float*)d_ws;                    // N*128 (Hh / H3)
    float* bufB  = bufA + (size_t)N * 128;          // N*128 (x / out)
    float* als   = bufB + (size_t)N * 128;          // 2N head-major
    float* ald   = als + (size_t)n2;                // 2N head-major
    int* deg     = (int*)(ald + (size_t)n2);        // N
    int* rowptr  = deg + N;                         // N+1
    int* cursor  = rowptr + (N + 1);                // N
    int* bsum    = cursor + N;                      // nb
    int* esorted = bsum + nb;                       // E

    dim3 blk(256);
    const int gE = (E + 255) / 256;
    const int nblk16 = (N + 15) / 16;

    // --- build CSR by dst (once; shared by all 3 layers) ---
    hipMemsetAsync(deg, 0, (size_t)N * sizeof(int), stream);
    k_hist<<<gE, blk, 0, stream>>>(dst, deg, E);
    k_scan1<<<nb, blk, 0, stream>>>(deg, bsum, N);
    k_scan3<<<nb, blk, 0, stream>>>(deg, bsum, rowptr, cursor, nb, N);
    k_scatter<<<gE, blk, 0, stream>>>(src, dst, cursor, esorted, E);

    // --- layer 1 (K=64, OUT=128) ---
    gemm_logits<64, 128, 64, true><<<(N + 63) / 64, blk, 0, stream>>>(feat, W1, a1s, a1d, bufA, als, ald, N);
    gat_gather_head<<<2 * nblk16, blk, 0, stream>>>(rowptr, esorted, als, ald, bufA, b1, bufB, N, nblk16);

    // --- layer 2 (K=128, OUT=128) ---
    gemm_logits<128, 128, 64, true><<<(N + 63) / 64, blk, 0, stream>>>(bufB, W2, a2s, a2d, bufA, als, ald, N);
    gat_gather_head<<<2 * nblk16, blk, 0, stream>>>(rowptr, esorted, als, ald, bufA, b2, bufB, N, nblk16);

    // --- layer 3 (K=128, OUT=32) ---
    gemm_logits<128, 32, 16, false><<<(N + 255) / 256, blk, 0, stream>>>(bufB, W3, a3s, a3d, bufA, als, ald, N);
    gat_gather_final<<<(N + 31) / 32, blk, 0, stream>>>(rowptr, esorted, als, ald, bufA, b3, (float*)d_out, N);
}

// Round 12
// 281.139 us; speedup vs baseline: 1.1736x; 1.1137x over previous
//
#include <hip/hip_runtime.h>
#include <hip/hip_fp16.h>

#define NEG_SLOPE 0.2f

__device__ __forceinline__ float lrelu(float x) { return x > 0.f ? x : NEG_SLOPE * x; }

// ---------------------------------------------------------------------------
// K1: h = X @ W (register-tiled, R3 tile) + per-(node,head) logits.
// HSPLIT=true (layers 1-2): H written HEAD-MAJOR as FP16: Hh[2][n][64] halves.
// HSPLIT=false (layer 3): H written fp32 [n][32].
// als/ald head-major: als[head*n + node], fp32.
// ---------------------------------------------------------------------------
template<int K, int OUT, int F, bool HSPLIT>
__global__ __launch_bounds__(256) void gemm_logits(
    const float* __restrict__ X, const float* __restrict__ W,
    const float* __restrict__ a_s, const float* __restrict__ a_d,
    float* __restrict__ HoutF, __half* __restrict__ HoutH,
    float* __restrict__ als, float* __restrict__ ald,
    int n)
{
    constexpr int TX = OUT / 4;
    constexpr int TY = 256 / TX;
    constexpr int MR = 8;
    constexpr int BM = TY * MR;
    constexpr int KC = 32;

    __shared__ __align__(16) float Xs[BM][KC];
    __shared__ __align__(16) float Ws[KC][OUT];

    const int tx = (int)threadIdx.x % TX;
    const int ty = (int)threadIdx.x / TX;
    const int r0 = blockIdx.x * BM;

    float4 acc[MR];
#pragma unroll
    for (int m = 0; m < MR; ++m) acc[m] = make_float4(0.f, 0.f, 0.f, 0.f);

    for (int kc = 0; kc < K; kc += KC) {
        __syncthreads();
        constexpr int XV = BM * KC / 4;
#pragma unroll
        for (int i = threadIdx.x; i < XV; i += 256) {
            int f = i * 4;
            int r = f / KC, k = f % KC;
            int gr = r0 + r;
            float4 v = make_float4(0.f, 0.f, 0.f, 0.f);
            if (gr < n) v = *(const float4*)(X + (size_t)gr * K + kc + k);
            *(float4*)(&Xs[r][k]) = v;
        }
        constexpr int WV = KC * OUT / 4;
#pragma unroll
        for (int i = threadIdx.x; i < WV; i += 256) {
            int f = i * 4;
            int k = f / OUT, c = f % OUT;
            *(float4*)(&Ws[k][c]) = *(const float4*)(W + (size_t)(kc + k) * OUT + c);
        }
        __syncthreads();

#pragma unroll
        for (int k4 = 0; k4 < KC; k4 += 4) {
            float4 xv[MR];
#pragma unroll
            for (int m = 0; m < MR; ++m)
                xv[m] = *(const float4*)(&Xs[ty * MR + m][k4]);
#pragma unroll
            for (int kk = 0; kk < 4; ++kk) {
                float4 wv = *(const float4*)(&Ws[k4 + kk][tx * 4]);
#pragma unroll
                for (int m = 0; m < MR; ++m) {
                    float xm = kk == 0 ? xv[m].x : kk == 1 ? xv[m].y : kk == 2 ? xv[m].z : xv[m].w;
                    acc[m].x = fmaf(xm, wv.x, acc[m].x);
                    acc[m].y = fmaf(xm, wv.y, acc[m].y);
                    acc[m].z = fmaf(xm, wv.z, acc[m].z);
                    acc[m].w = fmaf(xm, wv.w, acc[m].w);
                }
            }
        }
    }

    const float4 asv = *(const float4*)(a_s + tx * 4);
    const float4 adv = *(const float4*)(a_d + tx * 4);
    constexpr int UH = F / 4;                 // tx-lanes per head
    const int head = tx / UH;
#pragma unroll
    for (int m = 0; m < MR; ++m) {
        int gr = r0 + ty * MR + m;
        float ps = acc[m].x * asv.x + acc[m].y * asv.y + acc[m].z * asv.z + acc[m].w * asv.w;
        float pd = acc[m].x * adv.x + acc[m].y * adv.y + acc[m].z * adv.z + acc[m].w * adv.w;
#pragma unroll
        for (int off = UH / 2; off > 0; off >>= 1) {
            ps += __shfl_xor(ps, off, 64);
            pd += __shfl_xor(pd, off, 64);
        }
        if (gr < n) {
            if (HSPLIT) {
                union { __half h[4]; uint2 u; } pk;
                pk.h[0] = __float2half_rn(acc[m].x);
                pk.h[1] = __float2half_rn(acc[m].y);
                pk.h[2] = __float2half_rn(acc[m].z);
                pk.h[3] = __float2half_rn(acc[m].w);
                *(uint2*)(HoutH + ((size_t)head * n + gr) * F + (tx % UH) * 4) = pk.u;
            } else {
                *(float4*)(HoutF + (size_t)gr * OUT + tx * 4) = acc[m];
            }
            if ((tx % UH) == 0) {
                als[(size_t)head * n + gr] = ps;
                ald[(size_t)head * n + gr] = pd;
            }
        }
    }
}

// ---------------------------------------------------------------------------
// CSR build. hist -> per-tile sums -> merged scan -> scatter.
// ---------------------------------------------------------------------------
#define SCAN_TILE 1024

__global__ __launch_bounds__(256) void k_hist(const int* __restrict__ dst,
                                              int* __restrict__ deg, int E) {
    int e = blockIdx.x * 256 + threadIdx.x;
    if (e < E) atomicAdd(&deg[dst[e]], 1);
}

__global__ __launch_bounds__(256) void k_scan1(const int* __restrict__ deg,
                                               int* __restrict__ bsum, int N) {
    __shared__ int sm[256];
    int base = blockIdx.x * SCAN_TILE;
    int t = threadIdx.x;
    int s = 0;
#pragma unroll
    for (int j = 0; j < SCAN_TILE / 256; ++j) {
        int i = base + j * 256 + t;
        if (i < N) s += deg[i];
    }
    sm[t] = s;
    __syncthreads();
    for (int off = 128; off > 0; off >>= 1) {
        if (t < off) sm[t] += sm[t + off];
        __syncthreads();
    }
    if (t == 0) bsum[blockIdx.x] = sm[0];
}

__global__ __launch_bounds__(256) void k_scan3(const int* __restrict__ deg,
                                               const int* __restrict__ bsum,
                                               int* __restrict__ rowptr,
                                               int* __restrict__ cursor,
                                               int nb, int N) {
    __shared__ int sm[256];
    __shared__ int sme[256];
    int t = threadIdx.x;
    int v = (t < nb) ? bsum[t] : 0;
    sm[t] = v;
    __syncthreads();
    for (int off = 1; off < 256; off <<= 1) {
        int u = (t >= off) ? sm[t - off] : 0;
        __syncthreads();
        sm[t] += u;
        __syncthreads();
    }
    sme[t] = sm[t] - v;
    if (blockIdx.x == 0 && t == 255) rowptr[N] = sm[255];
    __syncthreads();
    const int boffv = sme[blockIdx.x];

    int base = blockIdx.x * SCAN_TILE;
    int i0 = base + t * 4;
    int d0 = 0, d1 = 0, d2 = 0, d3 = 0;
    if (i0 + 3 < N) {
        int4 dv = *(const int4*)(deg + i0);
        d0 = dv.x; d1 = dv.y; d2 = dv.z; d3 = dv.w;
    } else {
        if (i0 + 0 < N) d0 = deg[i0 + 0];
        if (i0 + 1 < N) d1 = deg[i0 + 1];
        if (i0 + 2 < N) d2 = deg[i0 + 2];
        if (i0 + 3 < N) d3 = deg[i0 + 3];
    }
    int tsum = d0 + d1 + d2 + d3;
    __syncthreads();
    sm[t] = tsum;
    __syncthreads();
    for (int off = 1; off < 256; off <<= 1) {
        int u = (t >= off) ? sm[t - off] : 0;
        __syncthreads();
        sm[t] += u;
        __syncthreads();
    }
    int run = boffv + sm[t] - tsum;
    if (i0 + 0 < N) { rowptr[i0 + 0] = run; cursor[i0 + 0] = run; run += d0; }
    if (i0 + 1 < N) { rowptr[i0 + 1] = run; cursor[i0 + 1] = run; run += d1; }
    if (i0 + 2 < N) { rowptr[i0 + 2] = run; cursor[i0 + 2] = run; run += d2; }
    if (i0 + 3 < N) { rowptr[i0 + 3] = run; cursor[i0 + 3] = run; run += d3; }
}

__global__ __launch_bounds__(256) void k_scatter(const int* __restrict__ src,
                                                 const int* __restrict__ dst,
                                                 int* __restrict__ cursor,
                                                 int* __restrict__ esorted, int E) {
    int e = blockIdx.x * 256 + threadIdx.x;
    if (e >= E) return;
    int p = atomicAdd(&cursor[dst[e]], 1);
    esorted[p] = src[e];
}

// ---------------------------------------------------------------------------
// B: head-phased gather, FP16 H. 16 lanes per (node,head); per edge: one
// 128 B Hh row (lane uint2 = 4 halves), uniform als scalar, fp32 math.
// Grid halves -> each phase works one 6.4 MB half-table.
// ---------------------------------------------------------------------------
__global__ __launch_bounds__(256) void gat_gather_head(
    const int* __restrict__ rowptr, const int* __restrict__ esorted,
    const float* __restrict__ als, const float* __restrict__ ald,
    const __half* __restrict__ Hh, const float* __restrict__ bias,
    float* __restrict__ out, int N, int nblk)
{
    const int head = (blockIdx.x >= nblk) ? 1 : 0;
    const int nodeblk = blockIdx.x - head * nblk;
    const int node = nodeblk * 16 + ((int)threadIdx.x >> 4);
    const int lane = (int)threadIdx.x & 15;
    if (node >= N) return;

    const float* __restrict__ alsh = als + (size_t)head * N;
    const float aldh = ald[(size_t)head * N + node];
    const __half* __restrict__ Ht = Hh + (size_t)head * N * 64;

    const float ws = expf(lrelu(alsh[node] + aldh));

    uint2 uo = *(const uint2*)(Ht + (size_t)node * 64 + lane * 4);
    float2 o01 = __half22float2(*reinterpret_cast<const __half2*>(&uo.x));
    float2 o23 = __half22float2(*reinterpret_cast<const __half2*>(&uo.y));
    float4 accA = make_float4(ws * o01.x, ws * o01.y, ws * o23.x, ws * o23.y);
    float4 accB = make_float4(0.f, 0.f, 0.f, 0.f);
    float4 accC = make_float4(0.f, 0.f, 0.f, 0.f);
    float4 accD = make_float4(0.f, 0.f, 0.f, 0.f);
    float den = ws;

    int p = rowptr[node];
    const int end = rowptr[node + 1];
    for (; p + 4 <= end; p += 4) {
        int s0 = esorted[p], s1 = esorted[p + 1], s2 = esorted[p + 2], s3 = esorted[p + 3];
        float l0 = alsh[s0], l1 = alsh[s1], l2 = alsh[s2], l3 = alsh[s3];
        uint2 u0 = *(const uint2*)(Ht + (size_t)s0 * 64 + lane * 4);
        uint2 u1 = *(const uint2*)(Ht + (size_t)s1 * 64 + lane * 4);
        uint2 u2 = *(const uint2*)(Ht + (size_t)s2 * 64 + lane * 4);
        uint2 u3 = *(const uint2*)(Ht + (size_t)s3 * 64 + lane * 4);
        float w0 = expf(lrelu(l0 + aldh));
        float w1 = expf(lrelu(l1 + aldh));
        float w2 = expf(lrelu(l2 + aldh));
        float w3 = expf(lrelu(l3 + aldh));
        float2 a01 = __half22float2(*reinterpret_cast<const __half2*>(&u0.x));
        float2 a23 = __half22float2(*reinterpret_cast<const __half2*>(&u0.y));
        float2 b01 = __half22float2(*reinterpret_cast<const __half2*>(&u1.x));
        float2 b23 = __half22float2(*reinterpret_cast<const __half2*>(&u1.y));
        float2 c01 = __half22float2(*reinterpret_cast<const __half2*>(&u2.x));
        float2 c23 = __half22float2(*reinterpret_cast<const __half2*>(&u2.y));
        float2 d01 = __half22float2(*reinterpret_cast<const __half2*>(&u3.x));
        float2 d23 = __half22float2(*reinterpret_cast<const __half2*>(&u3.y));
        accA.x = fmaf(w0, a01.x, accA.x); accA.y = fmaf(w0, a01.y, accA.y);
        accA.z = fmaf(w0, a23.x, accA.z); accA.w = fmaf(w0, a23.y, accA.w);
        accB.x = fmaf(w1, b01.x, accB.x); accB.y = fmaf(w1, b01.y, accB.y);
        accB.z = fmaf(w1, b23.x, accB.z); accB.w = fmaf(w1, b23.y, accB.w);
        accC.x = fmaf(w2, c01.x, accC.x); accC.y = fmaf(w2, c01.y, accC.y);
        accC.z = fmaf(w2, c23.x, accC.z); accC.w = fmaf(w2, c23.y, accC.w);
        accD.x = fmaf(w3, d01.x, accD.x); accD.y = fmaf(w3, d01.y, accD.y);
        accD.z = fmaf(w3, d23.x, accD.z); accD.w = fmaf(w3, d23.y, accD.w);
        den += (w0 + w1) + (w2 + w3);
    }
    for (; p < end; ++p) {
        int s0 = esorted[p];
        float w0 = expf(lrelu(alsh[s0] + aldh));
        uint2 u0 = *(const uint2*)(Ht + (size_t)s0 * 64 + lane * 4);
        float2 a01 = __half22float2(*reinterpret_cast<const __half2*>(&u0.x));
        float2 a23 = __half22float2(*reinterpret_cast<const __half2*>(&u0.y));
        accA.x = fmaf(w0, a01.x, accA.x); accA.y = fmaf(w0, a01.y, accA.y);
        accA.z = fmaf(w0, a23.x, accA.z); accA.w = fmaf(w0, a23.y, accA.w);
        den += w0;
    }

    const float r = 1.f / (den + 1e-16f);
    const float4 bv = *(const float4*)(bias + head * 64 + lane * 4);
    float4 v;
    v.x = (accA.x + accB.x + accC.x + accD.x) * r + bv.x;
    v.y = (accA.y + accB.y + accC.y + accD.y) * r + bv.y;
    v.z = (accA.z + accB.z + accC.z + accD.z) * r + bv.z;
    v.w = (accA.w + accB.w + accC.w + accD.w) * r + bv.w;
    v.x = v.x > 0.f ? v.x : 0.f;
    v.y = v.y > 0.f ? v.y : 0.f;
    v.z = v.z > 0.f ? v.z : 0.f;
    v.w = v.w > 0.f ? v.w : 0.f;
    *(float4*)(out + (size_t)node * 128 + head * 64 + lane * 4) = v;
}

// ---------------------------------------------------------------------------
// C: layer-3 gather (fp32 H) + fused mean/bias/softmax. 8 lanes per node.
// ---------------------------------------------------------------------------
__global__ __launch_bounds__(256) void gat_gather_final(
    const int* __restrict__ rowptr, const int* __restrict__ esorted,
    const float* __restrict__ als, const float* __restrict__ ald,
    const float* __restrict__ H3, const float* __restrict__ b3,
    float* __restrict__ out, int N)
{
    const int node = blockIdx.x * 32 + ((int)threadIdx.x >> 3);
    const int lane = (int)threadIdx.x & 7;
    if (node >= N) return;
    const int head = lane >> 2;
    const int sub = lane & 3;

    const float* __restrict__ alsh = als + (size_t)head * N;
    const float aldh = ald[(size_t)head * N + node];
    const float ws = expf(lrelu(alsh[node] + aldh));

    const float4 hown = *(const float4*)(H3 + (size_t)node * 32 + head * 16 + sub * 4);
    float4 accA = make_float4(ws * hown.x, ws * hown.y, ws * hown.z, ws * hown.w);
    float4 accB = make_float4(0.f, 0.f, 0.f, 0.f);
    float den = ws;

    int p = rowptr[node];
    const int end = rowptr[node + 1];
    for (; p + 2 <= end; p += 2) {
        int s0 = esorted[p], s1 = esorted[p + 1];
        float l0 = alsh[s0], l1 = alsh[s1];
        float4 h0 = *(const float4*)(H3 + (size_t)s0 * 32 + head * 16 + sub * 4);
        float4 h1 = *(const float4*)(H3 + (size_t)s1 * 32 + head * 16 + sub * 4);
        float w0 = expf(lrelu(l0 + aldh));
        float w1 = expf(lrelu(l1 + aldh));
        accA.x = fmaf(w0, h0.x, accA.x); accA.y = fmaf(w0, h0.y, accA.y);
        accA.z = fmaf(w0, h0.z, accA.z); accA.w = fmaf(w0, h0.w, accA.w);
        accB.x = fmaf(w1, h1.x, accB.x); accB.y = fmaf(w1, h1.y, accB.y);
        accB.z = fmaf(w1, h1.z, accB.z); accB.w = fmaf(w1, h1.w, accB.w);
        den += w0 + w1;
    }
    if (p < end) {
        int s0 = esorted[p];
        float4 h0 = *(const float4*)(H3 + (size_t)s0 * 32 + head * 16 + sub * 4);
        float w0 = expf(lrelu(alsh[s0] + aldh));
        accA.x = fmaf(w0, h0.x, accA.x); accA.y = fmaf(w0, h0.y, accA.y);
        accA.z = fmaf(w0, h0.z, accA.z); accA.w = fmaf(w0, h0.w, accA.w);
        den += w0;
    }

    const float r = 1.f / (den + 1e-16f);
    float4 a;
    a.x = (accA.x + accB.x) * r;
    a.y = (accA.y + accB.y) * r;
    a.z = (accA.z + accB.z) * r;
    a.w = (accA.w + accB.w) * r;
    float4 ap;
    ap.x = __shfl_xor(a.x, 4, 64);
    ap.y = __shfl_xor(a.y, 4, 64);
    ap.z = __shfl_xor(a.z, 4, 64);
    ap.w = __shfl_xor(a.w, 4, 64);
    const float4 bv = *(const float4*)(b3 + sub * 4);
    float4 v;
    v.x = 0.5f * (a.x + ap.x) + bv.x;
    v.y = 0.5f * (a.y + ap.y) + bv.y;
    v.z = 0.5f * (a.z + ap.z) + bv.z;
    v.w = 0.5f * (a.w + ap.w) + bv.w;
    float mx = fmaxf(fmaxf(v.x, v.y), fmaxf(v.z, v.w));
    mx = fmaxf(mx, __shfl_xor(mx, 1, 64));
    mx = fmaxf(mx, __shfl_xor(mx, 2, 64));
    float4 ex;
    ex.x = expf(v.x - mx);
    ex.y = expf(v.y - mx);
    ex.z = expf(v.z - mx);
    ex.w = expf(v.w - mx);
    float sum = ex.x + ex.y + ex.z + ex.w;
    sum += __shfl_xor(sum, 1, 64);
    sum += __shfl_xor(sum, 2, 64);
    const float rs = 1.f / sum;
    if (head == 0) {
        float4 o = make_float4(ex.x * rs, ex.y * rs, ex.z * rs, ex.w * rs);
        *(float4*)(out + (size_t)node * 16 + sub * 4) = o;
    }
}

// ---------------------------------------------------------------------------
extern "C" void kernel_launch(void* const* d_in, const int* in_sizes, int n_in,
                              void* d_out, int out_size, void* d_ws, size_t ws_size,
                              hipStream_t stream)
{
    const float* feat = (const float*)d_in[0];
    const int*   ei   = (const int*)d_in[1];
    const float* W1 = (const float*)d_in[2];
    const float* a1s = (const float*)d_in[3];
    const float* a1d = (const float*)d_in[4];
    const float* b1 = (const float*)d_in[5];
    const float* W2 = (const float*)d_in[6];
    const float* a2s = (const float*)d_in[7];
    const float* a2d = (const float*)d_in[8];
    const float* b2 = (const float*)d_in[9];
    const float* W3 = (const float*)d_in[10];
    const float* a3s = (const float*)d_in[11];
    const float* a3d = (const float*)d_in[12];
    const float* b3 = (const float*)d_in[13];

    const int N = in_sizes[0] / 64;
    const int E = in_sizes[1] / 2;
    const int* src = ei;
    const int* dst = ei + E;
    const int n2 = N * 2;
    const int nb = (N + SCAN_TILE - 1) / SCAN_TILE;

    // workspace layout (bufA used as fp16 Hh for layers 1-2, fp32 H3 for l3)
    float* bufA  = (float*)d_ws;                    // N*128 floats
    float* bufB  = bufA + (size_t)N * 128;          // N*128 (x / out)
    float* als   = bufB + (size_t)N * 128;          // 2N head-major
    float* ald   = als + (size_t)n2;                // 2N head-major
    int* deg     = (int*)(ald + (size_t)n2);        // N
    int* rowptr  = deg + N;                         // N+1
    int* cursor  = rowptr + (N + 1);                // N
    int* bsum    = cursor + N;                      // nb
    int* esorted = bsum + nb;                       // E
    __half* HhA  = (__half*)bufA;                   // 2*N*64 halves

    dim3 blk(256);
    const int gE = (E + 255) / 256;
    const int nblk16 = (N + 15) / 16;

    // --- build CSR by dst (once; shared by all 3 layers) ---
    hipMemsetAsync(deg, 0, (size_t)N * sizeof(int), stream);
    k_hist<<<gE, blk, 0, stream>>>(dst, deg, E);
    k_scan1<<<nb, blk, 0, stream>>>(deg, bsum, N);
    k_scan3<<<nb, blk, 0, stream>>>(deg, bsum, rowptr, cursor, nb, N);
    k_scatter<<<gE, blk, 0, stream>>>(src, dst, cursor, esorted, E);

    // --- layer 1 (K=64, OUT=128) ---
    gemm_logits<64, 128, 64, true><<<(N + 63) / 64, blk, 0, stream>>>(
        feat, W1, a1s, a1d, nullptr, HhA, als, ald, N);
    gat_gather_head<<<2 * nblk16, blk, 0, stream>>>(rowptr, esorted, als, ald, HhA, b1, bufB, N, nblk16);

    // --- layer 2 (K=128, OUT=128) ---
    gemm_logits<128, 128, 64, true><<<(N + 63) / 64, blk, 0, stream>>>(
        bufB, W2, a2s, a2d, nullptr, HhA, als, ald, N);
    gat_gather_head<<<2 * nblk16, blk, 0, stream>>>(rowptr, esorted, als, ald, HhA, b2, bufB, N, nblk16);

    // --- layer 3 (K=128, OUT=32) ---
    gemm_logits<128, 32, 16, false><<<(N + 255) / 256, blk, 0, stream>>>(
        bufB, W3, a3s, a3d, bufA, nullptr, als, ald, N);
    gat_gather_final<<<(N + 31) / 32, blk, 0, stream>>>(rowptr, esorted, als, ald, bufA, b3, (float*)d_out, N);
}

// Round 13
// 265.007 us; speedup vs baseline: 1.2450x; 1.0609x over previous
//
#include <hip/hip_runtime.h>
#include <hip/hip_fp16.h>

#define NEG_SLOPE 0.2f

__device__ __forceinline__ float lrelu(float x) { return x > 0.f ? x : NEG_SLOPE * x; }

// ---------------------------------------------------------------------------
// K1: h = X @ W (register-tiled, R3 tile) + per-(node,head) logits.
// HSPLIT=true (layers 1-2): H written HEAD-MAJOR as FP16: Hh[2][n][64] halves.
// HSPLIT=false (layer 3): H written fp32 [n][32].
// als/ald head-major: als[head*n + node], fp32.
// ---------------------------------------------------------------------------
template<int K, int OUT, int F, bool HSPLIT>
__global__ __launch_bounds__(256) void gemm_logits(
    const float* __restrict__ X, const float* __restrict__ W,
    const float* __restrict__ a_s, const float* __restrict__ a_d,
    float* __restrict__ HoutF, __half* __restrict__ HoutH,
    float* __restrict__ als, float* __restrict__ ald,
    int n)
{
    constexpr int TX = OUT / 4;
    constexpr int TY = 256 / TX;
    constexpr int MR = 8;
    constexpr int BM = TY * MR;
    constexpr int KC = 32;

    __shared__ __align__(16) float Xs[BM][KC];
    __shared__ __align__(16) float Ws[KC][OUT];

    const int tx = (int)threadIdx.x % TX;
    const int ty = (int)threadIdx.x / TX;
    const int r0 = blockIdx.x * BM;

    float4 acc[MR];
#pragma unroll
    for (int m = 0; m < MR; ++m) acc[m] = make_float4(0.f, 0.f, 0.f, 0.f);

    for (int kc = 0; kc < K; kc += KC) {
        __syncthreads();
        constexpr int XV = BM * KC / 4;
#pragma unroll
        for (int i = threadIdx.x; i < XV; i += 256) {
            int f = i * 4;
            int r = f / KC, k = f % KC;
            int gr = r0 + r;
            float4 v = make_float4(0.f, 0.f, 0.f, 0.f);
            if (gr < n) v = *(const float4*)(X + (size_t)gr * K + kc + k);
            *(float4*)(&Xs[r][k]) = v;
        }
        constexpr int WV = KC * OUT / 4;
#pragma unroll
        for (int i = threadIdx.x; i < WV; i += 256) {
            int f = i * 4;
            int k = f / OUT, c = f % OUT;
            *(float4*)(&Ws[k][c]) = *(const float4*)(W + (size_t)(kc + k) * OUT + c);
        }
        __syncthreads();

#pragma unroll
        for (int k4 = 0; k4 < KC; k4 += 4) {
            float4 xv[MR];
#pragma unroll
            for (int m = 0; m < MR; ++m)
                xv[m] = *(const float4*)(&Xs[ty * MR + m][k4]);
#pragma unroll
            for (int kk = 0; kk < 4; ++kk) {
                float4 wv = *(const float4*)(&Ws[k4 + kk][tx * 4]);
#pragma unroll
                for (int m = 0; m < MR; ++m) {
                    float xm = kk == 0 ? xv[m].x : kk == 1 ? xv[m].y : kk == 2 ? xv[m].z : xv[m].w;
                    acc[m].x = fmaf(xm, wv.x, acc[m].x);
                    acc[m].y = fmaf(xm, wv.y, acc[m].y);
                    acc[m].z = fmaf(xm, wv.z, acc[m].z);
                    acc[m].w = fmaf(xm, wv.w, acc[m].w);
                }
            }
        }
    }

    const float4 asv = *(const float4*)(a_s + tx * 4);
    const float4 adv = *(const float4*)(a_d + tx * 4);
    constexpr int UH = F / 4;                 // tx-lanes per head
    const int head = tx / UH;
#pragma unroll
    for (int m = 0; m < MR; ++m) {
        int gr = r0 + ty * MR + m;
        float ps = acc[m].x * asv.x + acc[m].y * asv.y + acc[m].z * asv.z + acc[m].w * asv.w;
        float pd = acc[m].x * adv.x + acc[m].y * adv.y + acc[m].z * adv.z + acc[m].w * adv.w;
#pragma unroll
        for (int off = UH / 2; off > 0; off >>= 1) {
            ps += __shfl_xor(ps, off, 64);
            pd += __shfl_xor(pd, off, 64);
        }
        if (gr < n) {
            if (HSPLIT) {
                union { __half h[4]; uint2 u; } pk;
                pk.h[0] = __float2half_rn(acc[m].x);
                pk.h[1] = __float2half_rn(acc[m].y);
                pk.h[2] = __float2half_rn(acc[m].z);
                pk.h[3] = __float2half_rn(acc[m].w);
                *(uint2*)(HoutH + ((size_t)head * n + gr) * F + (tx % UH) * 4) = pk.u;
            } else {
                *(float4*)(HoutF + (size_t)gr * OUT + tx * 4) = acc[m];
            }
            if ((tx % UH) == 0) {
                als[(size_t)head * n + gr] = ps;
                ald[(size_t)head * n + gr] = pd;
            }
        }
    }
}

// ---------------------------------------------------------------------------
// CSR build. hist -> per-tile sums -> merged scan -> XCD-partitioned scatter.
// ---------------------------------------------------------------------------
#define SCAN_TILE 1024

__global__ __launch_bounds__(256) void k_hist(const int* __restrict__ dst,
                                              int* __restrict__ deg, int E) {
    int e = blockIdx.x * 256 + threadIdx.x;
    if (e < E) atomicAdd(&deg[dst[e]], 1);
}

__global__ __launch_bounds__(256) void k_scan1(const int* __restrict__ deg,
                                               int* __restrict__ bsum, int N) {
    __shared__ int sm[256];
    int base = blockIdx.x * SCAN_TILE;
    int t = threadIdx.x;
    int s = 0;
#pragma unroll
    for (int j = 0; j < SCAN_TILE / 256; ++j) {
        int i = base + j * 256 + t;
        if (i < N) s += deg[i];
    }
    sm[t] = s;
    __syncthreads();
    for (int off = 128; off > 0; off >>= 1) {
        if (t < off) sm[t] += sm[t + off];
        __syncthreads();
    }
    if (t == 0) bsum[blockIdx.x] = sm[0];
}

__global__ __launch_bounds__(256) void k_scan3(const int* __restrict__ deg,
                                               const int* __restrict__ bsum,
                                               int* __restrict__ rowptr,
                                               int* __restrict__ cursor,
                                               int nb, int N) {
    __shared__ int sm[256];
    __shared__ int sme[256];
    int t = threadIdx.x;
    int v = (t < nb) ? bsum[t] : 0;
    sm[t] = v;
    __syncthreads();
    for (int off = 1; off < 256; off <<= 1) {
        int u = (t >= off) ? sm[t - off] : 0;
        __syncthreads();
        sm[t] += u;
        __syncthreads();
    }
    sme[t] = sm[t] - v;
    if (blockIdx.x == 0 && t == 255) rowptr[N] = sm[255];
    __syncthreads();
    const int boffv = sme[blockIdx.x];

    int base = blockIdx.x * SCAN_TILE;
    int i0 = base + t * 4;
    int d0 = 0, d1 = 0, d2 = 0, d3 = 0;
    if (i0 + 3 < N) {
        int4 dv = *(const int4*)(deg + i0);
        d0 = dv.x; d1 = dv.y; d2 = dv.z; d3 = dv.w;
    } else {
        if (i0 + 0 < N) d0 = deg[i0 + 0];
        if (i0 + 1 < N) d1 = deg[i0 + 1];
        if (i0 + 2 < N) d2 = deg[i0 + 2];
        if (i0 + 3 < N) d3 = deg[i0 + 3];
    }
    int tsum = d0 + d1 + d2 + d3;
    __syncthreads();
    sm[t] = tsum;
    __syncthreads();
    for (int off = 1; off < 256; off <<= 1) {
        int u = (t >= off) ? sm[t - off] : 0;
        __syncthreads();
        sm[t] += u;
        __syncthreads();
    }
    int run = boffv + sm[t] - tsum;
    if (i0 + 0 < N) { rowptr[i0 + 0] = run; cursor[i0 + 0] = run; run += d0; }
    if (i0 + 1 < N) { rowptr[i0 + 1] = run; cursor[i0 + 1] = run; run += d1; }
    if (i0 + 2 < N) { rowptr[i0 + 2] = run; cursor[i0 + 2] = run; run += d2; }
    if (i0 + 3 < N) { rowptr[i0 + 3] = run; cursor[i0 + 3] = run; run += d3; }
}

// XCD-partitioned scatter: 8 grid slices; slice s (= blockIdx & 7, matching
// the round-robin block->XCD mapping) handles only dst in [s*chunk,(s+1)*chunk)
// -> each XCD dirties only its own contiguous esorted/cursor region, so every
// 64B line is written back by exactly one XCD (kills the 16x write-back
// amplification of the unpartitioned scatter).
__global__ __launch_bounds__(256) void k_scatter_xcd(
    const int* __restrict__ src, const int* __restrict__ dst,
    int* __restrict__ cursor, int* __restrict__ esorted, int E, int chunk) {
    const int slice = blockIdx.x & 7;
    const int lo = slice * chunk;
    const int hi = lo + chunk;
    int e = (blockIdx.x >> 3) * 256 + threadIdx.x;
    if (e >= E) return;
    int d = dst[e];
    if (d < lo || d >= hi) return;
    int p = atomicAdd(&cursor[d], 1);
    esorted[p] = src[e];
}

// ---------------------------------------------------------------------------
// B: head-phased gather, FP16 H (R12, unchanged).
// ---------------------------------------------------------------------------
__global__ __launch_bounds__(256) void gat_gather_head(
    const int* __restrict__ rowptr, const int* __restrict__ esorted,
    const float* __restrict__ als, const float* __restrict__ ald,
    const __half* __restrict__ Hh, const float* __restrict__ bias,
    float* __restrict__ out, int N, int nblk)
{
    const int head = (blockIdx.x >= nblk) ? 1 : 0;
    const int nodeblk = blockIdx.x - head * nblk;
    const int node = nodeblk * 16 + ((int)threadIdx.x >> 4);
    const int lane = (int)threadIdx.x & 15;
    if (node >= N) return;

    const float* __restrict__ alsh = als + (size_t)head * N;
    const float aldh = ald[(size_t)head * N + node];
    const __half* __restrict__ Ht = Hh + (size_t)head * N * 64;

    const float ws = expf(lrelu(alsh[node] + aldh));

    uint2 uo = *(const uint2*)(Ht + (size_t)node * 64 + lane * 4);
    float2 o01 = __half22float2(*reinterpret_cast<const __half2*>(&uo.x));
    float2 o23 = __half22float2(*reinterpret_cast<const __half2*>(&uo.y));
    float4 accA = make_float4(ws * o01.x, ws * o01.y, ws * o23.x, ws * o23.y);
    float4 accB = make_float4(0.f, 0.f, 0.f, 0.f);
    float4 accC = make_float4(0.f, 0.f, 0.f, 0.f);
    float4 accD = make_float4(0.f, 0.f, 0.f, 0.f);
    float den = ws;

    int p = rowptr[node];
    const int end = rowptr[node + 1];
    for (; p + 4 <= end; p += 4) {
        int s0 = esorted[p], s1 = esorted[p + 1], s2 = esorted[p + 2], s3 = esorted[p + 3];
        float l0 = alsh[s0], l1 = alsh[s1], l2 = alsh[s2], l3 = alsh[s3];
        uint2 u0 = *(const uint2*)(Ht + (size_t)s0 * 64 + lane * 4);
        uint2 u1 = *(const uint2*)(Ht + (size_t)s1 * 64 + lane * 4);
        uint2 u2 = *(const uint2*)(Ht + (size_t)s2 * 64 + lane * 4);
        uint2 u3 = *(const uint2*)(Ht + (size_t)s3 * 64 + lane * 4);
        float w0 = expf(lrelu(l0 + aldh));
        float w1 = expf(lrelu(l1 + aldh));
        float w2 = expf(lrelu(l2 + aldh));
        float w3 = expf(lrelu(l3 + aldh));
        float2 a01 = __half22float2(*reinterpret_cast<const __half2*>(&u0.x));
        float2 a23 = __half22float2(*reinterpret_cast<const __half2*>(&u0.y));
        float2 b01 = __half22float2(*reinterpret_cast<const __half2*>(&u1.x));
        float2 b23 = __half22float2(*reinterpret_cast<const __half2*>(&u1.y));
        float2 c01 = __half22float2(*reinterpret_cast<const __half2*>(&u2.x));
        float2 c23 = __half22float2(*reinterpret_cast<const __half2*>(&u2.y));
        float2 d01 = __half22float2(*reinterpret_cast<const __half2*>(&u3.x));
        float2 d23 = __half22float2(*reinterpret_cast<const __half2*>(&u3.y));
        accA.x = fmaf(w0, a01.x, accA.x); accA.y = fmaf(w0, a01.y, accA.y);
        accA.z = fmaf(w0, a23.x, accA.z); accA.w = fmaf(w0, a23.y, accA.w);
        accB.x = fmaf(w1, b01.x, accB.x); accB.y = fmaf(w1, b01.y, accB.y);
        accB.z = fmaf(w1, b23.x, accB.z); accB.w = fmaf(w1, b23.y, accB.w);
        accC.x = fmaf(w2, c01.x, accC.x); accC.y = fmaf(w2, c01.y, accC.y);
        accC.z = fmaf(w2, c23.x, accC.z); accC.w = fmaf(w2, c23.y, accC.w);
        accD.x = fmaf(w3, d01.x, accD.x); accD.y = fmaf(w3, d01.y, accD.y);
        accD.z = fmaf(w3, d23.x, accD.z); accD.w = fmaf(w3, d23.y, accD.w);
        den += (w0 + w1) + (w2 + w3);
    }
    for (; p < end; ++p) {
        int s0 = esorted[p];
        float w0 = expf(lrelu(alsh[s0] + aldh));
        uint2 u0 = *(const uint2*)(Ht + (size_t)s0 * 64 + lane * 4);
        float2 a01 = __half22float2(*reinterpret_cast<const __half2*>(&u0.x));
        float2 a23 = __half22float2(*reinterpret_cast<const __half2*>(&u0.y));
        accA.x = fmaf(w0, a01.x, accA.x); accA.y = fmaf(w0, a01.y, accA.y);
        accA.z = fmaf(w0, a23.x, accA.z); accA.w = fmaf(w0, a23.y, accA.w);
        den += w0;
    }

    const float r = 1.f / (den + 1e-16f);
    const float4 bv = *(const float4*)(bias + head * 64 + lane * 4);
    float4 v;
    v.x = (accA.x + accB.x + accC.x + accD.x) * r + bv.x;
    v.y = (accA.y + accB.y + accC.y + accD.y) * r + bv.y;
    v.z = (accA.z + accB.z + accC.z + accD.z) * r + bv.z;
    v.w = (accA.w + accB.w + accC.w + accD.w) * r + bv.w;
    v.x = v.x > 0.f ? v.x : 0.f;
    v.y = v.y > 0.f ? v.y : 0.f;
    v.z = v.z > 0.f ? v.z : 0.f;
    v.w = v.w > 0.f ? v.w : 0.f;
    *(float4*)(out + (size_t)node * 128 + head * 64 + lane * 4) = v;
}

// ---------------------------------------------------------------------------
// C: layer-3 gather (fp32 H) + fused mean/bias/softmax (R12, unchanged).
// ---------------------------------------------------------------------------
__global__ __launch_bounds__(256) void gat_gather_final(
    const int* __restrict__ rowptr, const int* __restrict__ esorted,
    const float* __restrict__ als, const float* __restrict__ ald,
    const float* __restrict__ H3, const float* __restrict__ b3,
    float* __restrict__ out, int N)
{
    const int node = blockIdx.x * 32 + ((int)threadIdx.x >> 3);
    const int lane = (int)threadIdx.x & 7;
    if (node >= N) return;
    const int head = lane >> 2;
    const int sub = lane & 3;

    const float* __restrict__ alsh = als + (size_t)head * N;
    const float aldh = ald[(size_t)head * N + node];
    const float ws = expf(lrelu(alsh[node] + aldh));

    const float4 hown = *(const float4*)(H3 + (size_t)node * 32 + head * 16 + sub * 4);
    float4 accA = make_float4(ws * hown.x, ws * hown.y, ws * hown.z, ws * hown.w);
    float4 accB = make_float4(0.f, 0.f, 0.f, 0.f);
    float den = ws;

    int p = rowptr[node];
    const int end = rowptr[node + 1];
    for (; p + 2 <= end; p += 2) {
        int s0 = esorted[p], s1 = esorted[p + 1];
        float l0 = alsh[s0], l1 = alsh[s1];
        float4 h0 = *(const float4*)(H3 + (size_t)s0 * 32 + head * 16 + sub * 4);
        float4 h1 = *(const float4*)(H3 + (size_t)s1 * 32 + head * 16 + sub * 4);
        float w0 = expf(lrelu(l0 + aldh));
        float w1 = expf(lrelu(l1 + aldh));
        accA.x = fmaf(w0, h0.x, accA.x); accA.y = fmaf(w0, h0.y, accA.y);
        accA.z = fmaf(w0, h0.z, accA.z); accA.w = fmaf(w0, h0.w, accA.w);
        accB.x = fmaf(w1, h1.x, accB.x); accB.y = fmaf(w1, h1.y, accB.y);
        accB.z = fmaf(w1, h1.z, accB.z); accB.w = fmaf(w1, h1.w, accB.w);
        den += w0 + w1;
    }
    if (p < end) {
        int s0 = esorted[p];
        float4 h0 = *(const float4*)(H3 + (size_t)s0 * 32 + head * 16 + sub * 4);
        float w0 = expf(lrelu(alsh[s0] + aldh));
        accA.x = fmaf(w0, h0.x, accA.x); accA.y = fmaf(w0, h0.y, accA.y);
        accA.z = fmaf(w0, h0.z, accA.z); accA.w = fmaf(w0, h0.w, accA.w);
        den += w0;
    }

    const float r = 1.f / (den + 1e-16f);
    float4 a;
    a.x = (accA.x + accB.x) * r;
    a.y = (accA.y + accB.y) * r;
    a.z = (accA.z + accB.z) * r;
    a.w = (accA.w + accB.w) * r;
    float4 ap;
    ap.x = __shfl_xor(a.x, 4, 64);
    ap.y = __shfl_xor(a.y, 4, 64);
    ap.z = __shfl_xor(a.z, 4, 64);
    ap.w = __shfl_xor(a.w, 4, 64);
    const float4 bv = *(const float4*)(b3 + sub * 4);
    float4 v;
    v.x = 0.5f * (a.x + ap.x) + bv.x;
    v.y = 0.5f * (a.y + ap.y) + bv.y;
    v.z = 0.5f * (a.z + ap.z) + bv.z;
    v.w = 0.5f * (a.w + ap.w) + bv.w;
    float mx = fmaxf(fmaxf(v.x, v.y), fmaxf(v.z, v.w));
    mx = fmaxf(mx, __shfl_xor(mx, 1, 64));
    mx = fmaxf(mx, __shfl_xor(mx, 2, 64));
    float4 ex;
    ex.x = expf(v.x - mx);
    ex.y = expf(v.y - mx);
    ex.z = expf(v.z - mx);
    ex.w = expf(v.w - mx);
    float sum = ex.x + ex.y + ex.z + ex.w;
    sum += __shfl_xor(sum, 1, 64);
    sum += __shfl_xor(sum, 2, 64);
    const float rs = 1.f / sum;
    if (head == 0) {
        float4 o = make_float4(ex.x * rs, ex.y * rs, ex.z * rs, ex.w * rs);
        *(float4*)(out + (size_t)node * 16 + sub * 4) = o;
    }
}

// ---------------------------------------------------------------------------
extern "C" void kernel_launch(void* const* d_in, const int* in_sizes, int n_in,
                              void* d_out, int out_size, void* d_ws, size_t ws_size,
                              hipStream_t stream)
{
    const float* feat = (const float*)d_in[0];
    const int*   ei   = (const int*)d_in[1];
    const float* W1 = (const float*)d_in[2];
    const float* a1s = (const float*)d_in[3];
    const float* a1d = (const float*)d_in[4];
    const float* b1 = (const float*)d_in[5];
    const float* W2 = (const float*)d_in[6];
    const float* a2s = (const float*)d_in[7];
    const float* a2d = (const float*)d_in[8];
    const float* b2 = (const float*)d_in[9];
    const float* W3 = (const float*)d_in[10];
    const float* a3s = (const float*)d_in[11];
    const float* a3d = (const float*)d_in[12];
    const float* b3 = (const float*)d_in[13];

    const int N = in_sizes[0] / 64;
    const int E = in_sizes[1] / 2;
    const int* src = ei;
    const int* dst = ei + E;
    const int n2 = N * 2;
    const int nb = (N + SCAN_TILE - 1) / SCAN_TILE;

    // workspace layout (bufA used as fp16 Hh for layers 1-2, fp32 H3 for l3)
    float* bufA  = (float*)d_ws;                    // N*128 floats
    float* bufB  = bufA + (size_t)N * 128;          // N*128 (x / out)
    float* als   = bufB + (size_t)N * 128;          // 2N head-major
    float* ald   = als + (size_t)n2;                // 2N head-major
    int* deg     = (int*)(ald + (size_t)n2);        // N
    int* rowptr  = deg + N;                         // N+1
    int* cursor  = rowptr + (N + 1);                // N
    int* bsum    = cursor + N;                      // nb
    int* esorted = bsum + nb;                       // E
    __half* HhA  = (__half*)bufA;                   // 2*N*64 halves

    dim3 blk(256);
    const int gE = (E + 255) / 256;
    const int nblk16 = (N + 15) / 16;
    const int chunk = (N + 7) / 8;

    // --- build CSR by dst (once; shared by all 3 layers) ---
    hipMemsetAsync(deg, 0, (size_t)N * sizeof(int), stream);
    k_hist<<<gE, blk, 0, stream>>>(dst, deg, E);
    k_scan1<<<nb, blk, 0, stream>>>(deg, bsum, N);
    k_scan3<<<nb, blk, 0, stream>>>(deg, bsum, rowptr, cursor, nb, N);
    k_scatter_xcd<<<8 * gE, blk, 0, stream>>>(src, dst, cursor, esorted, E, chunk);

    // --- layer 1 (K=64, OUT=128) ---
    gemm_logits<64, 128, 64, true><<<(N + 63) / 64, blk, 0, stream>>>(
        feat, W1, a1s, a1d, nullptr, HhA, als, ald, N);
    gat_gather_head<<<2 * nblk16, blk, 0, stream>>>(rowptr, esorted, als, ald, HhA, b1, bufB, N, nblk16);

    // --- layer 2 (K=128, OUT=128) ---
    gemm_logits<128, 128, 64, true><<<(N + 63) / 64, blk, 0, stream>>>(
        bufB, W2, a2s, a2d, nullptr, HhA, als, ald, N);
    gat_gather_head<<<2 * nblk16, blk, 0, stream>>>(rowptr, esorted, als, ald, HhA, b2, bufB, N, nblk16);

    // --- layer 3 (K=128, OUT=32) ---
    gemm_logits<128, 32, 16, false><<<(N + 255) / 256, blk, 0, stream>>>(
        bufB, W3, a3s, a3d, bufA, nullptr, als, ald, N);
    gat_gather_final<<<(N + 31) / 32, blk, 0, stream>>>(rowptr, esorted, als, ald, bufA, b3, (float*)d_out, N);
}

// Round 14
// 259.778 us; speedup vs baseline: 1.2701x; 1.0201x over previous
//
#include <hip/hip_runtime.h>
#include <hip/hip_fp16.h>

#define NEG_SLOPE 0.2f

__device__ __forceinline__ float lrelu(float x) { return x > 0.f ? x : NEG_SLOPE * x; }

// ---------------------------------------------------------------------------
// K1: h = X @ W (register-tiled, R3 tile) + per-(node,head) logits.
// HSPLIT=true (layers 1-2): H written HEAD-MAJOR as FP16: Hh[2][n][64] halves.
// HSPLIT=false (layer 3): H written fp32 [n][32].
// als/ald head-major: als[head*n + node], fp32.
// ---------------------------------------------------------------------------
template<int K, int OUT, int F, bool HSPLIT>
__global__ __launch_bounds__(256) void gemm_logits(
    const float* __restrict__ X, const float* __restrict__ W,
    const float* __restrict__ a_s, const float* __restrict__ a_d,
    float* __restrict__ HoutF, __half* __restrict__ HoutH,
    float* __restrict__ als, float* __restrict__ ald,
    int n)
{
    constexpr int TX = OUT / 4;
    constexpr int TY = 256 / TX;
    constexpr int MR = 8;
    constexpr int BM = TY * MR;
    constexpr int KC = 32;

    __shared__ __align__(16) float Xs[BM][KC];
    __shared__ __align__(16) float Ws[KC][OUT];

    const int tx = (int)threadIdx.x % TX;
    const int ty = (int)threadIdx.x / TX;
    const int r0 = blockIdx.x * BM;

    float4 acc[MR];
#pragma unroll
    for (int m = 0; m < MR; ++m) acc[m] = make_float4(0.f, 0.f, 0.f, 0.f);

    for (int kc = 0; kc < K; kc += KC) {
        __syncthreads();
        constexpr int XV = BM * KC / 4;
#pragma unroll
        for (int i = threadIdx.x; i < XV; i += 256) {
            int f = i * 4;
            int r = f / KC, k = f % KC;
            int gr = r0 + r;
            float4 v = make_float4(0.f, 0.f, 0.f, 0.f);
            if (gr < n) v = *(const float4*)(X + (size_t)gr * K + kc + k);
            *(float4*)(&Xs[r][k]) = v;
        }
        constexpr int WV = KC * OUT / 4;
#pragma unroll
        for (int i = threadIdx.x; i < WV; i += 256) {
            int f = i * 4;
            int k = f / OUT, c = f % OUT;
            *(float4*)(&Ws[k][c]) = *(const float4*)(W + (size_t)(kc + k) * OUT + c);
        }
        __syncthreads();

#pragma unroll
        for (int k4 = 0; k4 < KC; k4 += 4) {
            float4 xv[MR];
#pragma unroll
            for (int m = 0; m < MR; ++m)
                xv[m] = *(const float4*)(&Xs[ty * MR + m][k4]);
#pragma unroll
            for (int kk = 0; kk < 4; ++kk) {
                float4 wv = *(const float4*)(&Ws[k4 + kk][tx * 4]);
#pragma unroll
                for (int m = 0; m < MR; ++m) {
                    float xm = kk == 0 ? xv[m].x : kk == 1 ? xv[m].y : kk == 2 ? xv[m].z : xv[m].w;
                    acc[m].x = fmaf(xm, wv.x, acc[m].x);
                    acc[m].y = fmaf(xm, wv.y, acc[m].y);
                    acc[m].z = fmaf(xm, wv.z, acc[m].z);
                    acc[m].w = fmaf(xm, wv.w, acc[m].w);
                }
            }
        }
    }

    const float4 asv = *(const float4*)(a_s + tx * 4);
    const float4 adv = *(const float4*)(a_d + tx * 4);
    constexpr int UH = F / 4;                 // tx-lanes per head
    const int head = tx / UH;
#pragma unroll
    for (int m = 0; m < MR; ++m) {
        int gr = r0 + ty * MR + m;
        float ps = acc[m].x * asv.x + acc[m].y * asv.y + acc[m].z * asv.z + acc[m].w * asv.w;
        float pd = acc[m].x * adv.x + acc[m].y * adv.y + acc[m].z * adv.z + acc[m].w * adv.w;
#pragma unroll
        for (int off = UH / 2; off > 0; off >>= 1) {
            ps += __shfl_xor(ps, off, 64);
            pd += __shfl_xor(pd, off, 64);
        }
        if (gr < n) {
            if (HSPLIT) {
                union { __half h[4]; uint2 u; } pk;
                pk.h[0] = __float2half_rn(acc[m].x);
                pk.h[1] = __float2half_rn(acc[m].y);
                pk.h[2] = __float2half_rn(acc[m].z);
                pk.h[3] = __float2half_rn(acc[m].w);
                *(uint2*)(HoutH + ((size_t)head * n + gr) * F + (tx % UH) * 4) = pk.u;
            } else {
                *(float4*)(HoutF + (size_t)gr * OUT + tx * 4) = acc[m];
            }
            if ((tx % UH) == 0) {
                als[(size_t)head * n + gr] = ps;
                ald[(size_t)head * n + gr] = pd;
            }
        }
    }
}

// ---------------------------------------------------------------------------
// CSR build. zero -> hist -> per-tile sums -> merged scan -> XCD scatter.
// ---------------------------------------------------------------------------
#define SCAN_TILE 1024

__global__ __launch_bounds__(256) void k_zero_int(int* __restrict__ p, int n) {
    int i = blockIdx.x * 256 + threadIdx.x;
    if (i < n) p[i] = 0;
}

__global__ __launch_bounds__(256) void k_hist(const int* __restrict__ dst,
                                              int* __restrict__ deg, int E) {
    int e = blockIdx.x * 256 + threadIdx.x;
    if (e < E) atomicAdd(&deg[dst[e]], 1);
}

__global__ __launch_bounds__(256) void k_scan1(const int* __restrict__ deg,
                                               int* __restrict__ bsum, int N) {
    __shared__ int sm[256];
    int base = blockIdx.x * SCAN_TILE;
    int t = threadIdx.x;
    int s = 0;
#pragma unroll
    for (int j = 0; j < SCAN_TILE / 256; ++j) {
        int i = base + j * 256 + t;
        if (i < N) s += deg[i];
    }
    sm[t] = s;
    __syncthreads();
    for (int off = 128; off > 0; off >>= 1) {
        if (t < off) sm[t] += sm[t + off];
        __syncthreads();
    }
    if (t == 0) bsum[blockIdx.x] = sm[0];
}

__global__ __launch_bounds__(256) void k_scan3(const int* __restrict__ deg,
                                               const int* __restrict__ bsum,
                                               int* __restrict__ rowptr,
                                               int* __restrict__ cursor,
                                               int nb, int N) {
    __shared__ int sm[256];
    __shared__ int sme[256];
    int t = threadIdx.x;
    int v = (t < nb) ? bsum[t] : 0;
    sm[t] = v;
    __syncthreads();
    for (int off = 1; off < 256; off <<= 1) {
        int u = (t >= off) ? sm[t - off] : 0;
        __syncthreads();
        sm[t] += u;
        __syncthreads();
    }
    sme[t] = sm[t] - v;
    if (blockIdx.x == 0 && t == 255) rowptr[N] = sm[255];
    __syncthreads();
    const int boffv = sme[blockIdx.x];

    int base = blockIdx.x * SCAN_TILE;
    int i0 = base + t * 4;
    int d0 = 0, d1 = 0, d2 = 0, d3 = 0;
    if (i0 + 3 < N) {
        int4 dv = *(const int4*)(deg + i0);
        d0 = dv.x; d1 = dv.y; d2 = dv.z; d3 = dv.w;
    } else {
        if (i0 + 0 < N) d0 = deg[i0 + 0];
        if (i0 + 1 < N) d1 = deg[i0 + 1];
        if (i0 + 2 < N) d2 = deg[i0 + 2];
        if (i0 + 3 < N) d3 = deg[i0 + 3];
    }
    int tsum = d0 + d1 + d2 + d3;
    __syncthreads();
    sm[t] = tsum;
    __syncthreads();
    for (int off = 1; off < 256; off <<= 1) {
        int u = (t >= off) ? sm[t - off] : 0;
        __syncthreads();
        sm[t] += u;
        __syncthreads();
    }
    int run = boffv + sm[t] - tsum;
    if (i0 + 0 < N) { rowptr[i0 + 0] = run; cursor[i0 + 0] = run; run += d0; }
    if (i0 + 1 < N) { rowptr[i0 + 1] = run; cursor[i0 + 1] = run; run += d1; }
    if (i0 + 2 < N) { rowptr[i0 + 2] = run; cursor[i0 + 2] = run; run += d2; }
    if (i0 + 3 < N) { rowptr[i0 + 3] = run; cursor[i0 + 3] = run; run += d3; }
}

// XCD-partitioned scatter (R13): slice = blockIdx & 7 handles only dst in its
// node range -> each XCD dirties only its own esorted/cursor lines.
__global__ __launch_bounds__(256) void k_scatter_xcd(
    const int* __restrict__ src, const int* __restrict__ dst,
    int* __restrict__ cursor, int* __restrict__ esorted, int E, int chunk) {
    const int slice = blockIdx.x & 7;
    const int lo = slice * chunk;
    const int hi = lo + chunk;
    int e = (blockIdx.x >> 3) * 256 + threadIdx.x;
    if (e >= E) return;
    int d = dst[e];
    if (d < lo || d >= hi) return;
    int p = atomicAdd(&cursor[d], 1);
    esorted[p] = src[e];
}

// ---------------------------------------------------------------------------
// B: head-phased gather, FP16 H, __expf weights.
// ---------------------------------------------------------------------------
__global__ __launch_bounds__(256) void gat_gather_head(
    const int* __restrict__ rowptr, const int* __restrict__ esorted,
    const float* __restrict__ als, const float* __restrict__ ald,
    const __half* __restrict__ Hh, const float* __restrict__ bias,
    float* __restrict__ out, int N, int nblk)
{
    const int head = (blockIdx.x >= nblk) ? 1 : 0;
    const int nodeblk = blockIdx.x - head * nblk;
    const int node = nodeblk * 16 + ((int)threadIdx.x >> 4);
    const int lane = (int)threadIdx.x & 15;
    if (node >= N) return;

    const float* __restrict__ alsh = als + (size_t)head * N;
    const float aldh = ald[(size_t)head * N + node];
    const __half* __restrict__ Ht = Hh + (size_t)head * N * 64;

    const float ws = __expf(lrelu(alsh[node] + aldh));

    uint2 uo = *(const uint2*)(Ht + (size_t)node * 64 + lane * 4);
    float2 o01 = __half22float2(*reinterpret_cast<const __half2*>(&uo.x));
    float2 o23 = __half22float2(*reinterpret_cast<const __half2*>(&uo.y));
    float4 accA = make_float4(ws * o01.x, ws * o01.y, ws * o23.x, ws * o23.y);
    float4 accB = make_float4(0.f, 0.f, 0.f, 0.f);
    float4 accC = make_float4(0.f, 0.f, 0.f, 0.f);
    float4 accD = make_float4(0.f, 0.f, 0.f, 0.f);
    float den = ws;

    int p = rowptr[node];
    const int end = rowptr[node + 1];
    for (; p + 4 <= end; p += 4) {
        int s0 = esorted[p], s1 = esorted[p + 1], s2 = esorted[p + 2], s3 = esorted[p + 3];
        float l0 = alsh[s0], l1 = alsh[s1], l2 = alsh[s2], l3 = alsh[s3];
        uint2 u0 = *(const uint2*)(Ht + (size_t)s0 * 64 + lane * 4);
        uint2 u1 = *(const uint2*)(Ht + (size_t)s1 * 64 + lane * 4);
        uint2 u2 = *(const uint2*)(Ht + (size_t)s2 * 64 + lane * 4);
        uint2 u3 = *(const uint2*)(Ht + (size_t)s3 * 64 + lane * 4);
        float w0 = __expf(lrelu(l0 + aldh));
        float w1 = __expf(lrelu(l1 + aldh));
        float w2 = __expf(lrelu(l2 + aldh));
        float w3 = __expf(lrelu(l3 + aldh));
        float2 a01 = __half22float2(*reinterpret_cast<const __half2*>(&u0.x));
        float2 a23 = __half22float2(*reinterpret_cast<const __half2*>(&u0.y));
        float2 b01 = __half22float2(*reinterpret_cast<const __half2*>(&u1.x));
        float2 b23 = __half22float2(*reinterpret_cast<const __half2*>(&u1.y));
        float2 c01 = __half22float2(*reinterpret_cast<const __half2*>(&u2.x));
        float2 c23 = __half22float2(*reinterpret_cast<const __half2*>(&u2.y));
        float2 d01 = __half22float2(*reinterpret_cast<const __half2*>(&u3.x));
        float2 d23 = __half22float2(*reinterpret_cast<const __half2*>(&u3.y));
        accA.x = fmaf(w0, a01.x, accA.x); accA.y = fmaf(w0, a01.y, accA.y);
        accA.z = fmaf(w0, a23.x, accA.z); accA.w = fmaf(w0, a23.y, accA.w);
        accB.x = fmaf(w1, b01.x, accB.x); accB.y = fmaf(w1, b01.y, accB.y);
        accB.z = fmaf(w1, b23.x, accB.z); accB.w = fmaf(w1, b23.y, accB.w);
        accC.x = fmaf(w2, c01.x, accC.x); accC.y = fmaf(w2, c01.y, accC.y);
        accC.z = fmaf(w2, c23.x, accC.z); accC.w = fmaf(w2, c23.y, accC.w);
        accD.x = fmaf(w3, d01.x, accD.x); accD.y = fmaf(w3, d01.y, accD.y);
        accD.z = fmaf(w3, d23.x, accD.z); accD.w = fmaf(w3, d23.y, accD.w);
        den += (w0 + w1) + (w2 + w3);
    }
    for (; p < end; ++p) {
        int s0 = esorted[p];
        float w0 = __expf(lrelu(alsh[s0] + aldh));
        uint2 u0 = *(const uint2*)(Ht + (size_t)s0 * 64 + lane * 4);
        float2 a01 = __half22float2(*reinterpret_cast<const __half2*>(&u0.x));
        float2 a23 = __half22float2(*reinterpret_cast<const __half2*>(&u0.y));
        accA.x = fmaf(w0, a01.x, accA.x); accA.y = fmaf(w0, a01.y, accA.y);
        accA.z = fmaf(w0, a23.x, accA.z); accA.w = fmaf(w0, a23.y, accA.w);
        den += w0;
    }

    const float r = 1.f / (den + 1e-16f);
    const float4 bv = *(const float4*)(bias + head * 64 + lane * 4);
    float4 v;
    v.x = (accA.x + accB.x + accC.x + accD.x) * r + bv.x;
    v.y = (accA.y + accB.y + accC.y + accD.y) * r + bv.y;
    v.z = (accA.z + accB.z + accC.z + accD.z) * r + bv.z;
    v.w = (accA.w + accB.w + accC.w + accD.w) * r + bv.w;
    v.x = v.x > 0.f ? v.x : 0.f;
    v.y = v.y > 0.f ? v.y : 0.f;
    v.z = v.z > 0.f ? v.z : 0.f;
    v.w = v.w > 0.f ? v.w : 0.f;
    *(float4*)(out + (size_t)node * 128 + head * 64 + lane * 4) = v;
}

// ---------------------------------------------------------------------------
// C: layer-3 gather (fp32 H) + fused mean/bias/softmax. __expf weights;
// final softmax keeps precise expf (16 values, output-facing).
// ---------------------------------------------------------------------------
__global__ __launch_bounds__(256) void gat_gather_final(
    const int* __restrict__ rowptr, const int* __restrict__ esorted,
    const float* __restrict__ als, const float* __restrict__ ald,
    const float* __restrict__ H3, const float* __restrict__ b3,
    float* __restrict__ out, int N)
{
    const int node = blockIdx.x * 32 + ((int)threadIdx.x >> 3);
    const int lane = (int)threadIdx.x & 7;
    if (node >= N) return;
    const int head = lane >> 2;
    const int sub = lane & 3;

    const float* __restrict__ alsh = als + (size_t)head * N;
    const float aldh = ald[(size_t)head * N + node];
    const float ws = __expf(lrelu(alsh[node] + aldh));

    const float4 hown = *(const float4*)(H3 + (size_t)node * 32 + head * 16 + sub * 4);
    float4 accA = make_float4(ws * hown.x, ws * hown.y, ws * hown.z, ws * hown.w);
    float4 accB = make_float4(0.f, 0.f, 0.f, 0.f);
    float den = ws;

    int p = rowptr[node];
    const int end = rowptr[node + 1];
    for (; p + 2 <= end; p += 2) {
        int s0 = esorted[p], s1 = esorted[p + 1];
        float l0 = alsh[s0], l1 = alsh[s1];
        float4 h0 = *(const float4*)(H3 + (size_t)s0 * 32 + head * 16 + sub * 4);
        float4 h1 = *(const float4*)(H3 + (size_t)s1 * 32 + head * 16 + sub * 4);
        float w0 = __expf(lrelu(l0 + aldh));
        float w1 = __expf(lrelu(l1 + aldh));
        accA.x = fmaf(w0, h0.x, accA.x); accA.y = fmaf(w0, h0.y, accA.y);
        accA.z = fmaf(w0, h0.z, accA.z); accA.w = fmaf(w0, h0.w, accA.w);
        accB.x = fmaf(w1, h1.x, accB.x); accB.y = fmaf(w1, h1.y, accB.y);
        accB.z = fmaf(w1, h1.z, accB.z); accB.w = fmaf(w1, h1.w, accB.w);
        den += w0 + w1;
    }
    if (p < end) {
        int s0 = esorted[p];
        float4 h0 = *(const float4*)(H3 + (size_t)s0 * 32 + head * 16 + sub * 4);
        float w0 = __expf(lrelu(alsh[s0] + aldh));
        accA.x = fmaf(w0, h0.x, accA.x); accA.y = fmaf(w0, h0.y, accA.y);
        accA.z = fmaf(w0, h0.z, accA.z); accA.w = fmaf(w0, h0.w, accA.w);
        den += w0;
    }

    const float r = 1.f / (den + 1e-16f);
    float4 a;
    a.x = (accA.x + accB.x) * r;
    a.y = (accA.y + accB.y) * r;
    a.z = (accA.z + accB.z) * r;
    a.w = (accA.w + accB.w) * r;
    float4 ap;
    ap.x = __shfl_xor(a.x, 4, 64);
    ap.y = __shfl_xor(a.y, 4, 64);
    ap.z = __shfl_xor(a.z, 4, 64);
    ap.w = __shfl_xor(a.w, 4, 64);
    const float4 bv = *(const float4*)(b3 + sub * 4);
    float4 v;
    v.x = 0.5f * (a.x + ap.x) + bv.x;
    v.y = 0.5f * (a.y + ap.y) + bv.y;
    v.z = 0.5f * (a.z + ap.z) + bv.z;
    v.w = 0.5f * (a.w + ap.w) + bv.w;
    float mx = fmaxf(fmaxf(v.x, v.y), fmaxf(v.z, v.w));
    mx = fmaxf(mx, __shfl_xor(mx, 1, 64));
    mx = fmaxf(mx, __shfl_xor(mx, 2, 64));
    float4 ex;
    ex.x = expf(v.x - mx);
    ex.y = expf(v.y - mx);
    ex.z = expf(v.z - mx);
    ex.w = expf(v.w - mx);
    float sum = ex.x + ex.y + ex.z + ex.w;
    sum += __shfl_xor(sum, 1, 64);
    sum += __shfl_xor(sum, 2, 64);
    const float rs = 1.f / sum;
    if (head == 0) {
        float4 o = make_float4(ex.x * rs, ex.y * rs, ex.z * rs, ex.w * rs);
        *(float4*)(out + (size_t)node * 16 + sub * 4) = o;
    }
}

// ---------------------------------------------------------------------------
extern "C" void kernel_launch(void* const* d_in, const int* in_sizes, int n_in,
                              void* d_out, int out_size, void* d_ws, size_t ws_size,
                              hipStream_t stream)
{
    const float* feat = (const float*)d_in[0];
    const int*   ei   = (const int*)d_in[1];
    const float* W1 = (const float*)d_in[2];
    const float* a1s = (const float*)d_in[3];
    const float* a1d = (const float*)d_in[4];
    const float* b1 = (const float*)d_in[5];
    const float* W2 = (const float*)d_in[6];
    const float* a2s = (const float*)d_in[7];
    const float* a2d = (const float*)d_in[8];
    const float* b2 = (const float*)d_in[9];
    const float* W3 = (const float*)d_in[10];
    const float* a3s = (const float*)d_in[11];
    const float* a3d = (const float*)d_in[12];
    const float* b3 = (const float*)d_in[13];

    const int N = in_sizes[0] / 64;
    const int E = in_sizes[1] / 2;
    const int* src = ei;
    const int* dst = ei + E;
    const int n2 = N * 2;
    const int nb = (N + SCAN_TILE - 1) / SCAN_TILE;

    // workspace layout (bufA used as fp16 Hh for layers 1-2, fp32 H3 for l3)
    float* bufA  = (float*)d_ws;                    // N*128 floats
    float* bufB  = bufA + (size_t)N * 128;          // N*128 (x / out)
    float* als   = bufB + (size_t)N * 128;          // 2N head-major
    float* ald   = als + (size_t)n2;                // 2N head-major
    int* deg     = (int*)(ald + (size_t)n2);        // N
    int* rowptr  = deg + N;                         // N+1
    int* cursor  = rowptr + (N + 1);                // N
    int* bsum    = cursor + N;                      // nb
    int* esorted = bsum + nb;                       // E
    __half* HhA  = (__half*)bufA;                   // 2*N*64 halves

    dim3 blk(256);
    const int gE = (E + 255) / 256;
    const int nblk16 = (N + 15) / 16;
    const int chunk = (N + 7) / 8;

    // --- build CSR by dst (once; shared by all 3 layers) ---
    k_zero_int<<<(N + 255) / 256, blk, 0, stream>>>(deg, N);
    k_hist<<<gE, blk, 0, stream>>>(dst, deg, E);
    k_scan1<<<nb, blk, 0, stream>>>(deg, bsum, N);
    k_scan3<<<nb, blk, 0, stream>>>(deg, bsum, rowptr, cursor, nb, N);
    k_scatter_xcd<<<8 * gE, blk, 0, stream>>>(src, dst, cursor, esorted, E, chunk);

    // --- layer 1 (K=64, OUT=128) ---
    gemm_logits<64, 128, 64, true><<<(N + 63) / 64, blk, 0, stream>>>(
        feat, W1, a1s, a1d, nullptr, HhA, als, ald, N);
    gat_gather_head<<<2 * nblk16, blk, 0, stream>>>(rowptr, esorted, als, ald, HhA, b1, bufB, N, nblk16);

    // --- layer 2 (K=128, OUT=128) ---
    gemm_logits<128, 128, 64, true><<<(N + 63) / 64, blk, 0, stream>>>(
        bufB, W2, a2s, a2d, nullptr, HhA, als, ald, N);
    gat_gather_head<<<2 * nblk16, blk, 0, stream>>>(rowptr, esorted, als, ald, HhA, b2, bufB, N, nblk16);

    // --- layer 3 (K=128, OUT=32) ---
    gemm_logits<128, 32, 16, false><<<(N + 255) / 256, blk, 0, stream>>>(
        bufB, W3, a3s, a3d, bufA, nullptr, als, ald, N);
    gat_gather_final<<<(N + 31) / 32, blk, 0, stream>>>(rowptr, esorted, als, ald, bufA, b3, (float*)d_out, N);
}

// Round 15
// 250.678 us; speedup vs baseline: 1.3162x; 1.0363x over previous
//
#include <hip/hip_runtime.h>
#include <hip/hip_fp16.h>

#define NEG_SLOPE 0.2f

__device__ __forceinline__ float lrelu(float x) { return x > 0.f ? x : NEG_SLOPE * x; }

using half8 = __attribute__((ext_vector_type(8))) _Float16;
using f32x4 = __attribute__((ext_vector_type(4))) float;

// ---------------------------------------------------------------------------
// MFMA GEMM (layers 1-2): h = X @ W, OUT=128, fp16 inputs, fp32 accum.
// Block = 256 thr = 4 waves; tile 64 rows; wave w owns rows w*16..w*16+15,
// all 8 column-tiles of 16. A row = lane&15, B col = lane&15, k-group =
// (lane>>4)*8 (same assumed map for A and B => any k-permutation cancels).
// C/D: col = lane&15, row = (lane>>4)*4 + j  [HW-verified m89/m91].
// Epilogue: H fp16 head-major Hh[2][n][64] + head-major logits als/ald.
// ---------------------------------------------------------------------------
template<int K>
__global__ __launch_bounds__(256) void gemm_mfma128(
    const float* __restrict__ X, const float* __restrict__ W,
    const float* __restrict__ a_s, const float* __restrict__ a_d,
    __half* __restrict__ HoutH, float* __restrict__ als, float* __restrict__ ald,
    int n)
{
    constexpr int KP = K + 8;                  // padded row (halves), 16B-aligned
    __shared__ __align__(16) _Float16 Xs[64 * KP];
    __shared__ __align__(16) _Float16 Wt[128 * KP];   // transposed: Wt[col][k]

    const int tid = (int)threadIdx.x;
    const int wid = tid >> 6;
    const int lane = tid & 63;
    const int r0 = blockIdx.x * 64;

    // stage X tile (fp32 -> fp16), coalesced float4 reads, zero-pad OOB rows
    for (int i = tid; i < 64 * K / 4; i += 256) {
        int r = i / (K / 4);
        int kc = (i % (K / 4)) * 4;
        int gr = r0 + r;
        float4 v = make_float4(0.f, 0.f, 0.f, 0.f);
        if (gr < n) v = *(const float4*)(X + (size_t)gr * K + kc);
        _Float16* d = &Xs[r * KP + kc];
        d[0] = (_Float16)v.x; d[1] = (_Float16)v.y;
        d[2] = (_Float16)v.z; d[3] = (_Float16)v.w;
    }
    // stage W transposed (fp32 -> fp16)
    for (int i = tid; i < K * 128 / 4; i += 256) {
        int k = i / 32;
        int c = (i % 32) * 4;
        float4 v = *(const float4*)(W + (size_t)k * 128 + c);
        Wt[(c + 0) * KP + k] = (_Float16)v.x;
        Wt[(c + 1) * KP + k] = (_Float16)v.y;
        Wt[(c + 2) * KP + k] = (_Float16)v.z;
        Wt[(c + 3) * KP + k] = (_Float16)v.w;
    }
    __syncthreads();

    const int arow = wid * 16 + (lane & 15);
    const int kg = (lane >> 4) * 8;

    f32x4 acc[8];
#pragma unroll
    for (int ct = 0; ct < 8; ++ct) acc[ct] = (f32x4){0.f, 0.f, 0.f, 0.f};

#pragma unroll
    for (int k0 = 0; k0 < K; k0 += 32) {
        half8 a = *(const half8*)&Xs[arow * KP + k0 + kg];
#pragma unroll
        for (int ct = 0; ct < 8; ++ct) {
            half8 b = *(const half8*)&Wt[(ct * 16 + (lane & 15)) * KP + k0 + kg];
            acc[ct] = __builtin_amdgcn_mfma_f32_16x16x32_f16(a, b, acc[ct], 0, 0, 0);
        }
    }

    // epilogue
    const int ccol = lane & 15;
    float asl[8], adl[8];
#pragma unroll
    for (int ct = 0; ct < 8; ++ct) {
        asl[ct] = a_s[ct * 16 + ccol];
        adl[ct] = a_d[ct * 16 + ccol];
    }
    const int crow = wid * 16 + (lane >> 4) * 4;

#pragma unroll
    for (int j = 0; j < 4; ++j) {
        int gr = r0 + crow + j;
        float ps0 = 0.f, pd0 = 0.f, ps1 = 0.f, pd1 = 0.f;
#pragma unroll
        for (int ct = 0; ct < 8; ++ct) {
            float h = acc[ct][j];
            if (ct < 4) { ps0 = fmaf(h, asl[ct], ps0); pd0 = fmaf(h, adl[ct], pd0); }
            else        { ps1 = fmaf(h, asl[ct], ps1); pd1 = fmaf(h, adl[ct], pd1); }
        }
#pragma unroll
        for (int off = 1; off < 16; off <<= 1) {
            ps0 += __shfl_xor(ps0, off, 64);
            pd0 += __shfl_xor(pd0, off, 64);
            ps1 += __shfl_xor(ps1, off, 64);
            pd1 += __shfl_xor(pd1, off, 64);
        }
        if (gr < n) {
            if (ccol == 0) {
                als[gr] = ps0;              ald[gr] = pd0;               // head 0
                als[(size_t)n + gr] = ps1;  ald[(size_t)n + gr] = pd1;   // head 1
            }
#pragma unroll
            for (int ct = 0; ct < 8; ++ct) {
                int col = ct * 16 + ccol;
                HoutH[((size_t)(col >> 6) * n + gr) * 64 + (col & 63)] =
                    __float2half_rn(acc[ct][j]);
            }
        }
    }
}

// ---------------------------------------------------------------------------
// Layer-3 GEMM: fp32 R3 register tile (output-facing, keep full precision).
// Writes H3 fp32 [n][32] + head-major logits.
// ---------------------------------------------------------------------------
template<int K, int OUT, int F>
__global__ __launch_bounds__(256) void gemm_logits(
    const float* __restrict__ X, const float* __restrict__ W,
    const float* __restrict__ a_s, const float* __restrict__ a_d,
    float* __restrict__ HoutF, float* __restrict__ als, float* __restrict__ ald,
    int n)
{
    constexpr int TX = OUT / 4;
    constexpr int TY = 256 / TX;
    constexpr int MR = 8;
    constexpr int BM = TY * MR;
    constexpr int KC = 32;

    __shared__ __align__(16) float Xs[BM][KC];
    __shared__ __align__(16) float Ws[KC][OUT];

    const int tx = (int)threadIdx.x % TX;
    const int ty = (int)threadIdx.x / TX;
    const int r0 = blockIdx.x * BM;

    float4 acc[MR];
#pragma unroll
    for (int m = 0; m < MR; ++m) acc[m] = make_float4(0.f, 0.f, 0.f, 0.f);

    for (int kc = 0; kc < K; kc += KC) {
        __syncthreads();
        constexpr int XV = BM * KC / 4;
#pragma unroll
        for (int i = threadIdx.x; i < XV; i += 256) {
            int f = i * 4;
            int r = f / KC, k = f % KC;
            int gr = r0 + r;
            float4 v = make_float4(0.f, 0.f, 0.f, 0.f);
            if (gr < n) v = *(const float4*)(X + (size_t)gr * K + kc + k);
            *(float4*)(&Xs[r][k]) = v;
        }
        constexpr int WV = KC * OUT / 4;
#pragma unroll
        for (int i = threadIdx.x; i < WV; i += 256) {
            int f = i * 4;
            int k = f / OUT, c = f % OUT;
            *(float4*)(&Ws[k][c]) = *(const float4*)(W + (size_t)(kc + k) * OUT + c);
        }
        __syncthreads();

#pragma unroll
        for (int k4 = 0; k4 < KC; k4 += 4) {
            float4 xv[MR];
#pragma unroll
            for (int m = 0; m < MR; ++m)
                xv[m] = *(const float4*)(&Xs[ty * MR + m][k4]);
#pragma unroll
            for (int kk = 0; kk < 4; ++kk) {
                float4 wv = *(const float4*)(&Ws[k4 + kk][tx * 4]);
#pragma unroll
                for (int m = 0; m < MR; ++m) {
                    float xm = kk == 0 ? xv[m].x : kk == 1 ? xv[m].y : kk == 2 ? xv[m].z : xv[m].w;
                    acc[m].x = fmaf(xm, wv.x, acc[m].x);
                    acc[m].y = fmaf(xm, wv.y, acc[m].y);
                    acc[m].z = fmaf(xm, wv.z, acc[m].z);
                    acc[m].w = fmaf(xm, wv.w, acc[m].w);
                }
            }
        }
    }

    const float4 asv = *(const float4*)(a_s + tx * 4);
    const float4 adv = *(const float4*)(a_d + tx * 4);
    constexpr int UH = F / 4;
    const int head = tx / UH;
#pragma unroll
    for (int m = 0; m < MR; ++m) {
        int gr = r0 + ty * MR + m;
        float ps = acc[m].x * asv.x + acc[m].y * asv.y + acc[m].z * asv.z + acc[m].w * asv.w;
        float pd = acc[m].x * adv.x + acc[m].y * adv.y + acc[m].z * adv.z + acc[m].w * adv.w;
#pragma unroll
        for (int off = UH / 2; off > 0; off >>= 1) {
            ps += __shfl_xor(ps, off, 64);
            pd += __shfl_xor(pd, off, 64);
        }
        if (gr < n) {
            *(float4*)(HoutF + (size_t)gr * OUT + tx * 4) = acc[m];
            if ((tx % UH) == 0) {
                als[(size_t)head * n + gr] = ps;
                ald[(size_t)head * n + gr] = pd;
            }
        }
    }
}

// ---------------------------------------------------------------------------
// CSR build. zero -> hist -> per-tile sums -> merged scan -> XCD scatter.
// ---------------------------------------------------------------------------
#define SCAN_TILE 1024

__global__ __launch_bounds__(256) void k_zero_int(int* __restrict__ p, int n) {
    int i = blockIdx.x * 256 + threadIdx.x;
    if (i < n) p[i] = 0;
}

__global__ __launch_bounds__(256) void k_hist(const int* __restrict__ dst,
                                              int* __restrict__ deg, int E) {
    int e = blockIdx.x * 256 + threadIdx.x;
    if (e < E) atomicAdd(&deg[dst[e]], 1);
}

__global__ __launch_bounds__(256) void k_scan1(const int* __restrict__ deg,
                                               int* __restrict__ bsum, int N) {
    __shared__ int sm[256];
    int base = blockIdx.x * SCAN_TILE;
    int t = threadIdx.x;
    int s = 0;
#pragma unroll
    for (int j = 0; j < SCAN_TILE / 256; ++j) {
        int i = base + j * 256 + t;
        if (i < N) s += deg[i];
    }
    sm[t] = s;
    __syncthreads();
    for (int off = 128; off > 0; off >>= 1) {
        if (t < off) sm[t] += sm[t + off];
        __syncthreads();
    }
    if (t == 0) bsum[blockIdx.x] = sm[0];
}

__global__ __launch_bounds__(256) void k_scan3(const int* __restrict__ deg,
                                               const int* __restrict__ bsum,
                                               int* __restrict__ rowptr,
                                               int* __restrict__ cursor,
                                               int nb, int N) {
    __shared__ int sm[256];
    __shared__ int sme[256];
    int t = threadIdx.x;
    int v = (t < nb) ? bsum[t] : 0;
    sm[t] = v;
    __syncthreads();
    for (int off = 1; off < 256; off <<= 1) {
        int u = (t >= off) ? sm[t - off] : 0;
        __syncthreads();
        sm[t] += u;
        __syncthreads();
    }
    sme[t] = sm[t] - v;
    if (blockIdx.x == 0 && t == 255) rowptr[N] = sm[255];
    __syncthreads();
    const int boffv = sme[blockIdx.x];

    int base = blockIdx.x * SCAN_TILE;
    int i0 = base + t * 4;
    int d0 = 0, d1 = 0, d2 = 0, d3 = 0;
    if (i0 + 3 < N) {
        int4 dv = *(const int4*)(deg + i0);
        d0 = dv.x; d1 = dv.y; d2 = dv.z; d3 = dv.w;
    } else {
        if (i0 + 0 < N) d0 = deg[i0 + 0];
        if (i0 + 1 < N) d1 = deg[i0 + 1];
        if (i0 + 2 < N) d2 = deg[i0 + 2];
        if (i0 + 3 < N) d3 = deg[i0 + 3];
    }
    int tsum = d0 + d1 + d2 + d3;
    __syncthreads();
    sm[t] = tsum;
    __syncthreads();
    for (int off = 1; off < 256; off <<= 1) {
        int u = (t >= off) ? sm[t - off] : 0;
        __syncthreads();
        sm[t] += u;
        __syncthreads();
    }
    int run = boffv + sm[t] - tsum;
    if (i0 + 0 < N) { rowptr[i0 + 0] = run; cursor[i0 + 0] = run; run += d0; }
    if (i0 + 1 < N) { rowptr[i0 + 1] = run; cursor[i0 + 1] = run; run += d1; }
    if (i0 + 2 < N) { rowptr[i0 + 2] = run; cursor[i0 + 2] = run; run += d2; }
    if (i0 + 3 < N) { rowptr[i0 + 3] = run; cursor[i0 + 3] = run; run += d3; }
}

// XCD-partitioned scatter: slice = blockIdx & 7 handles only dst in its range.
__global__ __launch_bounds__(256) void k_scatter_xcd(
    const int* __restrict__ src, const int* __restrict__ dst,
    int* __restrict__ cursor, int* __restrict__ esorted, int E, int chunk) {
    const int slice = blockIdx.x & 7;
    const int lo = slice * chunk;
    const int hi = lo + chunk;
    int e = (blockIdx.x >> 3) * 256 + threadIdx.x;
    if (e >= E) return;
    int d = dst[e];
    if (d < lo || d >= hi) return;
    int p = atomicAdd(&cursor[d], 1);
    esorted[p] = src[e];
}

// ---------------------------------------------------------------------------
// B: head-phased gather, FP16 H, __expf weights (R14, unchanged).
// ---------------------------------------------------------------------------
__global__ __launch_bounds__(256) void gat_gather_head(
    const int* __restrict__ rowptr, const int* __restrict__ esorted,
    const float* __restrict__ als, const float* __restrict__ ald,
    const __half* __restrict__ Hh, const float* __restrict__ bias,
    float* __restrict__ out, int N, int nblk)
{
    const int head = (blockIdx.x >= nblk) ? 1 : 0;
    const int nodeblk = blockIdx.x - head * nblk;
    const int node = nodeblk * 16 + ((int)threadIdx.x >> 4);
    const int lane = (int)threadIdx.x & 15;
    if (node >= N) return;

    const float* __restrict__ alsh = als + (size_t)head * N;
    const float aldh = ald[(size_t)head * N + node];
    const __half* __restrict__ Ht = Hh + (size_t)head * N * 64;

    const float ws = __expf(lrelu(alsh[node] + aldh));

    uint2 uo = *(const uint2*)(Ht + (size_t)node * 64 + lane * 4);
    float2 o01 = __half22float2(*reinterpret_cast<const __half2*>(&uo.x));
    float2 o23 = __half22float2(*reinterpret_cast<const __half2*>(&uo.y));
    float4 accA = make_float4(ws * o01.x, ws * o01.y, ws * o23.x, ws * o23.y);
    float4 accB = make_float4(0.f, 0.f, 0.f, 0.f);
    float4 accC = make_float4(0.f, 0.f, 0.f, 0.f);
    float4 accD = make_float4(0.f, 0.f, 0.f, 0.f);
    float den = ws;

    int p = rowptr[node];
    const int end = rowptr[node + 1];
    for (; p + 4 <= end; p += 4) {
        int s0 = esorted[p], s1 = esorted[p + 1], s2 = esorted[p + 2], s3 = esorted[p + 3];
        float l0 = alsh[s0], l1 = alsh[s1], l2 = alsh[s2], l3 = alsh[s3];
        uint2 u0 = *(const uint2*)(Ht + (size_t)s0 * 64 + lane * 4);
        uint2 u1 = *(const uint2*)(Ht + (size_t)s1 * 64 + lane * 4);
        uint2 u2 = *(const uint2*)(Ht + (size_t)s2 * 64 + lane * 4);
        uint2 u3 = *(const uint2*)(Ht + (size_t)s3 * 64 + lane * 4);
        float w0 = __expf(lrelu(l0 + aldh));
        float w1 = __expf(lrelu(l1 + aldh));
        float w2 = __expf(lrelu(l2 + aldh));
        float w3 = __expf(lrelu(l3 + aldh));
        float2 a01 = __half22float2(*reinterpret_cast<const __half2*>(&u0.x));
        float2 a23 = __half22float2(*reinterpret_cast<const __half2*>(&u0.y));
        float2 b01 = __half22float2(*reinterpret_cast<const __half2*>(&u1.x));
        float2 b23 = __half22float2(*reinterpret_cast<const __half2*>(&u1.y));
        float2 c01 = __half22float2(*reinterpret_cast<const __half2*>(&u2.x));
        float2 c23 = __half22float2(*reinterpret_cast<const __half2*>(&u2.y));
        float2 d01 = __half22float2(*reinterpret_cast<const __half2*>(&u3.x));
        float2 d23 = __half22float2(*reinterpret_cast<const __half2*>(&u3.y));
        accA.x = fmaf(w0, a01.x, accA.x); accA.y = fmaf(w0, a01.y, accA.y);
        accA.z = fmaf(w0, a23.x, accA.z); accA.w = fmaf(w0, a23.y, accA.w);
        accB.x = fmaf(w1, b01.x, accB.x); accB.y = fmaf(w1, b01.y, accB.y);
        accB.z = fmaf(w1, b23.x, accB.z); accB.w = fmaf(w1, b23.y, accB.w);
        accC.x = fmaf(w2, c01.x, accC.x); accC.y = fmaf(w2, c01.y, accC.y);
        accC.z = fmaf(w2, c23.x, accC.z); accC.w = fmaf(w2, c23.y, accC.w);
        accD.x = fmaf(w3, d01.x, accD.x); accD.y = fmaf(w3, d01.y, accD.y);
        accD.z = fmaf(w3, d23.x, accD.z); accD.w = fmaf(w3, d23.y, accD.w);
        den += (w0 + w1) + (w2 + w3);
    }
    for (; p < end; ++p) {
        int s0 = esorted[p];
        float w0 = __expf(lrelu(alsh[s0] + aldh));
        uint2 u0 = *(const uint2*)(Ht + (size_t)s0 * 64 + lane * 4);
        float2 a01 = __half22float2(*reinterpret_cast<const __half2*>(&u0.x));
        float2 a23 = __half22float2(*reinterpret_cast<const __half2*>(&u0.y));
        accA.x = fmaf(w0, a01.x, accA.x); accA.y = fmaf(w0, a01.y, accA.y);
        accA.z = fmaf(w0, a23.x, accA.z); accA.w = fmaf(w0, a23.y, accA.w);
        den += w0;
    }

    const float r = 1.f / (den + 1e-16f);
    const float4 bv = *(const float4*)(bias + head * 64 + lane * 4);
    float4 v;
    v.x = (accA.x + accB.x + accC.x + accD.x) * r + bv.x;
    v.y = (accA.y + accB.y + accC.y + accD.y) * r + bv.y;
    v.z = (accA.z + accB.z + accC.z + accD.z) * r + bv.z;
    v.w = (accA.w + accB.w + accC.w + accD.w) * r + bv.w;
    v.x = v.x > 0.f ? v.x : 0.f;
    v.y = v.y > 0.f ? v.y : 0.f;
    v.z = v.z > 0.f ? v.z : 0.f;
    v.w = v.w > 0.f ? v.w : 0.f;
    *(float4*)(out + (size_t)node * 128 + head * 64 + lane * 4) = v;
}

// ---------------------------------------------------------------------------
// C: layer-3 gather (fp32 H) + fused mean/bias/softmax (R14, unchanged).
// ---------------------------------------------------------------------------
__global__ __launch_bounds__(256) void gat_gather_final(
    const int* __restrict__ rowptr, const int* __restrict__ esorted,
    const float* __restrict__ als, const float* __restrict__ ald,
    const float* __restrict__ H3, const float* __restrict__ b3,
    float* __restrict__ out, int N)
{
    const int node = blockIdx.x * 32 + ((int)threadIdx.x >> 3);
    const int lane = (int)threadIdx.x & 7;
    if (node >= N) return;
    const int head = lane >> 2;
    const int sub = lane & 3;

    const float* __restrict__ alsh = als + (size_t)head * N;
    const float aldh = ald[(size_t)head * N + node];
    const float ws = __expf(lrelu(alsh[node] + aldh));

    const float4 hown = *(const float4*)(H3 + (size_t)node * 32 + head * 16 + sub * 4);
    float4 accA = make_float4(ws * hown.x, ws * hown.y, ws * hown.z, ws * hown.w);
    float4 accB = make_float4(0.f, 0.f, 0.f, 0.f);
    float den = ws;

    int p = rowptr[node];
    const int end = rowptr[node + 1];
    for (; p + 2 <= end; p += 2) {
        int s0 = esorted[p], s1 = esorted[p + 1];
        float l0 = alsh[s0], l1 = alsh[s1];
        float4 h0 = *(const float4*)(H3 + (size_t)s0 * 32 + head * 16 + sub * 4);
        float4 h1 = *(const float4*)(H3 + (size_t)s1 * 32 + head * 16 + sub * 4);
        float w0 = __expf(lrelu(l0 + aldh));
        float w1 = __expf(lrelu(l1 + aldh));
        accA.x = fmaf(w0, h0.x, accA.x); accA.y = fmaf(w0, h0.y, accA.y);
        accA.z = fmaf(w0, h0.z, accA.z); accA.w = fmaf(w0, h0.w, accA.w);
        accB.x = fmaf(w1, h1.x, accB.x); accB.y = fmaf(w1, h1.y, accB.y);
        accB.z = fmaf(w1, h1.z, accB.z); accB.w = fmaf(w1, h1.w, accB.w);
        den += w0 + w1;
    }
    if (p < end) {
        int s0 = esorted[p];
        float4 h0 = *(const float4*)(H3 + (size_t)s0 * 32 + head * 16 + sub * 4);
        float w0 = __expf(lrelu(alsh[s0] + aldh));
        accA.x = fmaf(w0, h0.x, accA.x); accA.y = fmaf(w0, h0.y, accA.y);
        accA.z = fmaf(w0, h0.z, accA.z); accA.w = fmaf(w0, h0.w, accA.w);
        den += w0;
    }

    const float r = 1.f / (den + 1e-16f);
    float4 a;
    a.x = (accA.x + accB.x) * r;
    a.y = (accA.y + accB.y) * r;
    a.z = (accA.z + accB.z) * r;
    a.w = (accA.w + accB.w) * r;
    float4 ap;
    ap.x = __shfl_xor(a.x, 4, 64);
    ap.y = __shfl_xor(a.y, 4, 64);
    ap.z = __shfl_xor(a.z, 4, 64);
    ap.w = __shfl_xor(a.w, 4, 64);
    const float4 bv = *(const float4*)(b3 + sub * 4);
    float4 v;
    v.x = 0.5f * (a.x + ap.x) + bv.x;
    v.y = 0.5f * (a.y + ap.y) + bv.y;
    v.z = 0.5f * (a.z + ap.z) + bv.z;
    v.w = 0.5f * (a.w + ap.w) + bv.w;
    float mx = fmaxf(fmaxf(v.x, v.y), fmaxf(v.z, v.w));
    mx = fmaxf(mx, __shfl_xor(mx, 1, 64));
    mx = fmaxf(mx, __shfl_xor(mx, 2, 64));
    float4 ex;
    ex.x = expf(v.x - mx);
    ex.y = expf(v.y - mx);
    ex.z = expf(v.z - mx);
    ex.w = expf(v.w - mx);
    float sum = ex.x + ex.y + ex.z + ex.w;
    sum += __shfl_xor(sum, 1, 64);
    sum += __shfl_xor(sum, 2, 64);
    const float rs = 1.f / sum;
    if (head == 0) {
        float4 o = make_float4(ex.x * rs, ex.y * rs, ex.z * rs, ex.w * rs);
        *(float4*)(out + (size_t)node * 16 + sub * 4) = o;
    }
}

// ---------------------------------------------------------------------------
extern "C" void kernel_launch(void* const* d_in, const int* in_sizes, int n_in,
                              void* d_out, int out_size, void* d_ws, size_t ws_size,
                              hipStream_t stream)
{
    const float* feat = (const float*)d_in[0];
    const int*   ei   = (const int*)d_in[1];
    const float* W1 = (const float*)d_in[2];
    const float* a1s = (const float*)d_in[3];
    const float* a1d = (const float*)d_in[4];
    const float* b1 = (const float*)d_in[5];
    const float* W2 = (const float*)d_in[6];
    const float* a2s = (const float*)d_in[7];
    const float* a2d = (const float*)d_in[8];
    const float* b2 = (const float*)d_in[9];
    const float* W3 = (const float*)d_in[10];
    const float* a3s = (const float*)d_in[11];
    const float* a3d = (const float*)d_in[12];
    const float* b3 = (const float*)d_in[13];

    const int N = in_sizes[0] / 64;
    const int E = in_sizes[1] / 2;
    const int* src = ei;
    const int* dst = ei + E;
    const int n2 = N * 2;
    const int nb = (N + SCAN_TILE - 1) / SCAN_TILE;

    // workspace layout (bufA = fp16 Hh for layers 1-2, fp32 H3 for layer 3)
    float* bufA  = (float*)d_ws;                    // N*128 floats
    float* bufB  = bufA + (size_t)N * 128;          // N*128 (x / out)
    float* als   = bufB + (size_t)N * 128;          // 2N head-major
    float* ald   = als + (size_t)n2;                // 2N head-major
    int* deg     = (int*)(ald + (size_t)n2);        // N
    int* rowptr  = deg + N;                         // N+1
    int* cursor  = rowptr + (N + 1);                // N
    int* bsum    = cursor + N;                      // nb
    int* esorted = bsum + nb;                       // E
    __half* HhA  = (__half*)bufA;                   // 2*N*64 halves

    dim3 blk(256);
    const int gE = (E + 255) / 256;
    const int nblk16 = (N + 15) / 16;
    const int gM = (N + 63) / 64;
    const int chunk = (N + 7) / 8;

    // --- build CSR by dst (once; shared by all 3 layers) ---
    k_zero_int<<<(N + 255) / 256, blk, 0, stream>>>(deg, N);
    k_hist<<<gE, blk, 0, stream>>>(dst, deg, E);
    k_scan1<<<nb, blk, 0, stream>>>(deg, bsum, N);
    k_scan3<<<nb, blk, 0, stream>>>(deg, bsum, rowptr, cursor, nb, N);
    k_scatter_xcd<<<8 * gE, blk, 0, stream>>>(src, dst, cursor, esorted, E, chunk);

    // --- layer 1 (K=64, OUT=128, MFMA fp16) ---
    gemm_mfma128<64><<<gM, blk, 0, stream>>>(feat, W1, a1s, a1d, HhA, als, ald, N);
    gat_gather_head<<<2 * nblk16, blk, 0, stream>>>(rowptr, esorted, als, ald, HhA, b1, bufB, N, nblk16);

    // --- layer 2 (K=128, OUT=128, MFMA fp16) ---
    gemm_mfma128<128><<<gM, blk, 0, stream>>>(bufB, W2, a2s, a2d, HhA, als, ald, N);
    gat_gather_head<<<2 * nblk16, blk, 0, stream>>>(rowptr, esorted, als, ald, HhA, b2, bufB, N, nblk16);

    // --- layer 3 (K=128, OUT=32, fp32) ---
    gemm_logits<128, 32, 16><<<(N + 255) / 256, blk, 0, stream>>>(
        bufB, W3, a3s, a3d, bufA, als, ald, N);
    gat_gather_final<<<(N + 31) / 32, blk, 0, stream>>>(rowptr, esorted, als, ald, bufA, b3, (float*)d_out, N);
}

// Round 16
// 234.625 us; speedup vs baseline: 1.4062x; 1.0684x over previous
//
#include <hip/hip_runtime.h>
#include <hip/hip_fp16.h>

#define NEG_SLOPE 0.2f

__device__ __forceinline__ float lrelu(float x) { return x > 0.f ? x : NEG_SLOPE * x; }

using half8 = __attribute__((ext_vector_type(8))) _Float16;
using f32x4 = __attribute__((ext_vector_type(4))) float;

// ---------------------------------------------------------------------------
// MFMA GEMM (layers 1-2): h = X @ W, OUT=128, fp16 inputs, fp32 accum.
// Block = 256 thr = 4 waves; tile 64 rows; wave w owns rows w*16..w*16+15,
// all 8 column-tiles of 16. Same assumed k-map for A and B (permutation
// cancels); C/D: col = lane&15, row = (lane>>4)*4 + j  [HW-verified m89/m91].
// Epilogue: H fp16 head-major Hh[2][n][64] + head-major logits als/ald.
// ---------------------------------------------------------------------------
template<int K>
__global__ __launch_bounds__(256) void gemm_mfma128(
    const float* __restrict__ X, const float* __restrict__ W,
    const float* __restrict__ a_s, const float* __restrict__ a_d,
    __half* __restrict__ HoutH, float* __restrict__ als, float* __restrict__ ald,
    int n)
{
    constexpr int KP = K + 8;
    __shared__ __align__(16) _Float16 Xs[64 * KP];
    __shared__ __align__(16) _Float16 Wt[128 * KP];   // transposed: Wt[col][k]

    const int tid = (int)threadIdx.x;
    const int wid = tid >> 6;
    const int lane = tid & 63;
    const int r0 = blockIdx.x * 64;

    for (int i = tid; i < 64 * K / 4; i += 256) {
        int r = i / (K / 4);
        int kc = (i % (K / 4)) * 4;
        int gr = r0 + r;
        float4 v = make_float4(0.f, 0.f, 0.f, 0.f);
        if (gr < n) v = *(const float4*)(X + (size_t)gr * K + kc);
        _Float16* d = &Xs[r * KP + kc];
        d[0] = (_Float16)v.x; d[1] = (_Float16)v.y;
        d[2] = (_Float16)v.z; d[3] = (_Float16)v.w;
    }
    for (int i = tid; i < K * 128 / 4; i += 256) {
        int k = i / 32;
        int c = (i % 32) * 4;
        float4 v = *(const float4*)(W + (size_t)k * 128 + c);
        Wt[(c + 0) * KP + k] = (_Float16)v.x;
        Wt[(c + 1) * KP + k] = (_Float16)v.y;
        Wt[(c + 2) * KP + k] = (_Float16)v.z;
        Wt[(c + 3) * KP + k] = (_Float16)v.w;
    }
    __syncthreads();

    const int arow = wid * 16 + (lane & 15);
    const int kg = (lane >> 4) * 8;

    f32x4 acc[8];
#pragma unroll
    for (int ct = 0; ct < 8; ++ct) acc[ct] = (f32x4){0.f, 0.f, 0.f, 0.f};

#pragma unroll
    for (int k0 = 0; k0 < K; k0 += 32) {
        half8 a = *(const half8*)&Xs[arow * KP + k0 + kg];
#pragma unroll
        for (int ct = 0; ct < 8; ++ct) {
            half8 b = *(const half8*)&Wt[(ct * 16 + (lane & 15)) * KP + k0 + kg];
            acc[ct] = __builtin_amdgcn_mfma_f32_16x16x32_f16(a, b, acc[ct], 0, 0, 0);
        }
    }

    const int ccol = lane & 15;
    float asl[8], adl[8];
#pragma unroll
    for (int ct = 0; ct < 8; ++ct) {
        asl[ct] = a_s[ct * 16 + ccol];
        adl[ct] = a_d[ct * 16 + ccol];
    }
    const int crow = wid * 16 + (lane >> 4) * 4;

#pragma unroll
    for (int j = 0; j < 4; ++j) {
        int gr = r0 + crow + j;
        float ps0 = 0.f, pd0 = 0.f, ps1 = 0.f, pd1 = 0.f;
#pragma unroll
        for (int ct = 0; ct < 8; ++ct) {
            float h = acc[ct][j];
            if (ct < 4) { ps0 = fmaf(h, asl[ct], ps0); pd0 = fmaf(h, adl[ct], pd0); }
            else        { ps1 = fmaf(h, asl[ct], ps1); pd1 = fmaf(h, adl[ct], pd1); }
        }
#pragma unroll
        for (int off = 1; off < 16; off <<= 1) {
            ps0 += __shfl_xor(ps0, off, 64);
            pd0 += __shfl_xor(pd0, off, 64);
            ps1 += __shfl_xor(ps1, off, 64);
            pd1 += __shfl_xor(pd1, off, 64);
        }
        if (gr < n) {
            if (ccol == 0) {
                als[gr] = ps0;              ald[gr] = pd0;
                als[(size_t)n + gr] = ps1;  ald[(size_t)n + gr] = pd1;
            }
#pragma unroll
            for (int ct = 0; ct < 8; ++ct) {
                int col = ct * 16 + ccol;
                HoutH[((size_t)(col >> 6) * n + gr) * 64 + (col & 63)] =
                    __float2half_rn(acc[ct][j]);
            }
        }
    }
}

// ---------------------------------------------------------------------------
// MFMA GEMM (layer 3): h3 = X @ W, OUT=32 (2 column-tiles = 2 heads).
// Same fragment scheme. H3 stored fp16 [n][32]; head-major logits.
// ---------------------------------------------------------------------------
template<int K>
__global__ __launch_bounds__(256) void gemm_mfma32(
    const float* __restrict__ X, const float* __restrict__ W,
    const float* __restrict__ a_s, const float* __restrict__ a_d,
    __half* __restrict__ H3h, float* __restrict__ als, float* __restrict__ ald,
    int n)
{
    constexpr int KP = K + 8;
    __shared__ __align__(16) _Float16 Xs[64 * KP];
    __shared__ __align__(16) _Float16 Wt[32 * KP];

    const int tid = (int)threadIdx.x;
    const int wid = tid >> 6;
    const int lane = tid & 63;
    const int r0 = blockIdx.x * 64;

    for (int i = tid; i < 64 * K / 4; i += 256) {
        int r = i / (K / 4);
        int kc = (i % (K / 4)) * 4;
        int gr = r0 + r;
        float4 v = make_float4(0.f, 0.f, 0.f, 0.f);
        if (gr < n) v = *(const float4*)(X + (size_t)gr * K + kc);
        _Float16* d = &Xs[r * KP + kc];
        d[0] = (_Float16)v.x; d[1] = (_Float16)v.y;
        d[2] = (_Float16)v.z; d[3] = (_Float16)v.w;
    }
    for (int i = tid; i < K * 32 / 4; i += 256) {
        int k = i / 8;
        int c = (i % 8) * 4;
        float4 v = *(const float4*)(W + (size_t)k * 32 + c);
        Wt[(c + 0) * KP + k] = (_Float16)v.x;
        Wt[(c + 1) * KP + k] = (_Float16)v.y;
        Wt[(c + 2) * KP + k] = (_Float16)v.z;
        Wt[(c + 3) * KP + k] = (_Float16)v.w;
    }
    __syncthreads();

    const int arow = wid * 16 + (lane & 15);
    const int kg = (lane >> 4) * 8;

    f32x4 acc[2];
    acc[0] = (f32x4){0.f, 0.f, 0.f, 0.f};
    acc[1] = (f32x4){0.f, 0.f, 0.f, 0.f};

#pragma unroll
    for (int k0 = 0; k0 < K; k0 += 32) {
        half8 a = *(const half8*)&Xs[arow * KP + k0 + kg];
#pragma unroll
        for (int ct = 0; ct < 2; ++ct) {
            half8 b = *(const half8*)&Wt[(ct * 16 + (lane & 15)) * KP + k0 + kg];
            acc[ct] = __builtin_amdgcn_mfma_f32_16x16x32_f16(a, b, acc[ct], 0, 0, 0);
        }
    }

    const int ccol = lane & 15;
    const float as0 = a_s[ccol], as1 = a_s[16 + ccol];
    const float ad0 = a_d[ccol], ad1 = a_d[16 + ccol];
    const int crow = wid * 16 + (lane >> 4) * 4;

#pragma unroll
    for (int j = 0; j < 4; ++j) {
        int gr = r0 + crow + j;
        float ps0 = acc[0][j] * as0, pd0 = acc[0][j] * ad0;
        float ps1 = acc[1][j] * as1, pd1 = acc[1][j] * ad1;
#pragma unroll
        for (int off = 1; off < 16; off <<= 1) {
            ps0 += __shfl_xor(ps0, off, 64);
            pd0 += __shfl_xor(pd0, off, 64);
            ps1 += __shfl_xor(ps1, off, 64);
            pd1 += __shfl_xor(pd1, off, 64);
        }
        if (gr < n) {
            if (ccol == 0) {
                als[gr] = ps0;              ald[gr] = pd0;
                als[(size_t)n + gr] = ps1;  ald[(size_t)n + gr] = pd1;
            }
            H3h[(size_t)gr * 32 + ccol]      = __float2half_rn(acc[0][j]);
            H3h[(size_t)gr * 32 + 16 + ccol] = __float2half_rn(acc[1][j]);
        }
    }
}

// ---------------------------------------------------------------------------
// CSR build. zero -> hist -> per-tile sums -> merged scan -> XCD scatter.
// ---------------------------------------------------------------------------
#define SCAN_TILE 1024

__global__ __launch_bounds__(256) void k_zero_int(int* __restrict__ p, int n) {
    int i = blockIdx.x * 256 + threadIdx.x;
    if (i < n) p[i] = 0;
}

__global__ __launch_bounds__(256) void k_hist(const int* __restrict__ dst,
                                              int* __restrict__ deg, int E) {
    int e = blockIdx.x * 256 + threadIdx.x;
    if (e < E) atomicAdd(&deg[dst[e]], 1);
}

__global__ __launch_bounds__(256) void k_scan1(const int* __restrict__ deg,
                                               int* __restrict__ bsum, int N) {
    __shared__ int sm[256];
    int base = blockIdx.x * SCAN_TILE;
    int t = threadIdx.x;
    int s = 0;
#pragma unroll
    for (int j = 0; j < SCAN_TILE / 256; ++j) {
        int i = base + j * 256 + t;
        if (i < N) s += deg[i];
    }
    sm[t] = s;
    __syncthreads();
    for (int off = 128; off > 0; off >>= 1) {
        if (t < off) sm[t] += sm[t + off];
        __syncthreads();
    }
    if (t == 0) bsum[blockIdx.x] = sm[0];
}

__global__ __launch_bounds__(256) void k_scan3(const int* __restrict__ deg,
                                               const int* __restrict__ bsum,
                                               int* __restrict__ rowptr,
                                               int* __restrict__ cursor,
                                               int nb, int N) {
    __shared__ int sm[256];
    __shared__ int sme[256];
    int t = threadIdx.x;
    int v = (t < nb) ? bsum[t] : 0;
    sm[t] = v;
    __syncthreads();
    for (int off = 1; off < 256; off <<= 1) {
        int u = (t >= off) ? sm[t - off] : 0;
        __syncthreads();
        sm[t] += u;
        __syncthreads();
    }
    sme[t] = sm[t] - v;
    if (blockIdx.x == 0 && t == 255) rowptr[N] = sm[255];
    __syncthreads();
    const int boffv = sme[blockIdx.x];

    int base = blockIdx.x * SCAN_TILE;
    int i0 = base + t * 4;
    int d0 = 0, d1 = 0, d2 = 0, d3 = 0;
    if (i0 + 3 < N) {
        int4 dv = *(const int4*)(deg + i0);
        d0 = dv.x; d1 = dv.y; d2 = dv.z; d3 = dv.w;
    } else {
        if (i0 + 0 < N) d0 = deg[i0 + 0];
        if (i0 + 1 < N) d1 = deg[i0 + 1];
        if (i0 + 2 < N) d2 = deg[i0 + 2];
        if (i0 + 3 < N) d3 = deg[i0 + 3];
    }
    int tsum = d0 + d1 + d2 + d3;
    __syncthreads();
    sm[t] = tsum;
    __syncthreads();
    for (int off = 1; off < 256; off <<= 1) {
        int u = (t >= off) ? sm[t - off] : 0;
        __syncthreads();
        sm[t] += u;
        __syncthreads();
    }
    int run = boffv + sm[t] - tsum;
    if (i0 + 0 < N) { rowptr[i0 + 0] = run; cursor[i0 + 0] = run; run += d0; }
    if (i0 + 1 < N) { rowptr[i0 + 1] = run; cursor[i0 + 1] = run; run += d1; }
    if (i0 + 2 < N) { rowptr[i0 + 2] = run; cursor[i0 + 2] = run; run += d2; }
    if (i0 + 3 < N) { rowptr[i0 + 3] = run; cursor[i0 + 3] = run; run += d3; }
}

// XCD-partitioned scatter: slice = blockIdx & 7 handles only dst in its range.
__global__ __launch_bounds__(256) void k_scatter_xcd(
    const int* __restrict__ src, const int* __restrict__ dst,
    int* __restrict__ cursor, int* __restrict__ esorted, int E, int chunk) {
    const int slice = blockIdx.x & 7;
    const int lo = slice * chunk;
    const int hi = lo + chunk;
    int e = (blockIdx.x >> 3) * 256 + threadIdx.x;
    if (e >= E) return;
    int d = dst[e];
    if (d < lo || d >= hi) return;
    int p = atomicAdd(&cursor[d], 1);
    esorted[p] = src[e];
}

// ---------------------------------------------------------------------------
// B: head-phased gather, FP16 H, __expf weights (unchanged).
// ---------------------------------------------------------------------------
__global__ __launch_bounds__(256) void gat_gather_head(
    const int* __restrict__ rowptr, const int* __restrict__ esorted,
    const float* __restrict__ als, const float* __restrict__ ald,
    const __half* __restrict__ Hh, const float* __restrict__ bias,
    float* __restrict__ out, int N, int nblk)
{
    const int head = (blockIdx.x >= nblk) ? 1 : 0;
    const int nodeblk = blockIdx.x - head * nblk;
    const int node = nodeblk * 16 + ((int)threadIdx.x >> 4);
    const int lane = (int)threadIdx.x & 15;
    if (node >= N) return;

    const float* __restrict__ alsh = als + (size_t)head * N;
    const float aldh = ald[(size_t)head * N + node];
    const __half* __restrict__ Ht = Hh + (size_t)head * N * 64;

    const float ws = __expf(lrelu(alsh[node] + aldh));

    uint2 uo = *(const uint2*)(Ht + (size_t)node * 64 + lane * 4);
    float2 o01 = __half22float2(*reinterpret_cast<const __half2*>(&uo.x));
    float2 o23 = __half22float2(*reinterpret_cast<const __half2*>(&uo.y));
    float4 accA = make_float4(ws * o01.x, ws * o01.y, ws * o23.x, ws * o23.y);
    float4 accB = make_float4(0.f, 0.f, 0.f, 0.f);
    float4 accC = make_float4(0.f, 0.f, 0.f, 0.f);
    float4 accD = make_float4(0.f, 0.f, 0.f, 0.f);
    float den = ws;

    int p = rowptr[node];
    const int end = rowptr[node + 1];
    for (; p + 4 <= end; p += 4) {
        int s0 = esorted[p], s1 = esorted[p + 1], s2 = esorted[p + 2], s3 = esorted[p + 3];
        float l0 = alsh[s0], l1 = alsh[s1], l2 = alsh[s2], l3 = alsh[s3];
        uint2 u0 = *(const uint2*)(Ht + (size_t)s0 * 64 + lane * 4);
        uint2 u1 = *(const uint2*)(Ht + (size_t)s1 * 64 + lane * 4);
        uint2 u2 = *(const uint2*)(Ht + (size_t)s2 * 64 + lane * 4);
        uint2 u3 = *(const uint2*)(Ht + (size_t)s3 * 64 + lane * 4);
        float w0 = __expf(lrelu(l0 + aldh));
        float w1 = __expf(lrelu(l1 + aldh));
        float w2 = __expf(lrelu(l2 + aldh));
        float w3 = __expf(lrelu(l3 + aldh));
        float2 a01 = __half22float2(*reinterpret_cast<const __half2*>(&u0.x));
        float2 a23 = __half22float2(*reinterpret_cast<const __half2*>(&u0.y));
        float2 b01 = __half22float2(*reinterpret_cast<const __half2*>(&u1.x));
        float2 b23 = __half22float2(*reinterpret_cast<const __half2*>(&u1.y));
        float2 c01 = __half22float2(*reinterpret_cast<const __half2*>(&u2.x));
        float2 c23 = __half22float2(*reinterpret_cast<const __half2*>(&u2.y));
        float2 d01 = __half22float2(*reinterpret_cast<const __half2*>(&u3.x));
        float2 d23 = __half22float2(*reinterpret_cast<const __half2*>(&u3.y));
        accA.x = fmaf(w0, a01.x, accA.x); accA.y = fmaf(w0, a01.y, accA.y);
        accA.z = fmaf(w0, a23.x, accA.z); accA.w = fmaf(w0, a23.y, accA.w);
        accB.x = fmaf(w1, b01.x, accB.x); accB.y = fmaf(w1, b01.y, accB.y);
        accB.z = fmaf(w1, b23.x, accB.z); accB.w = fmaf(w1, b23.y, accB.w);
        accC.x = fmaf(w2, c01.x, accC.x); accC.y = fmaf(w2, c01.y, accC.y);
        accC.z = fmaf(w2, c23.x, accC.z); accC.w = fmaf(w2, c23.y, accC.w);
        accD.x = fmaf(w3, d01.x, accD.x); accD.y = fmaf(w3, d01.y, accD.y);
        accD.z = fmaf(w3, d23.x, accD.z); accD.w = fmaf(w3, d23.y, accD.w);
        den += (w0 + w1) + (w2 + w3);
    }
    for (; p < end; ++p) {
        int s0 = esorted[p];
        float w0 = __expf(lrelu(alsh[s0] + aldh));
        uint2 u0 = *(const uint2*)(Ht + (size_t)s0 * 64 + lane * 4);
        float2 a01 = __half22float2(*reinterpret_cast<const __half2*>(&u0.x));
        float2 a23 = __half22float2(*reinterpret_cast<const __half2*>(&u0.y));
        accA.x = fmaf(w0, a01.x, accA.x); accA.y = fmaf(w0, a01.y, accA.y);
        accA.z = fmaf(w0, a23.x, accA.z); accA.w = fmaf(w0, a23.y, accA.w);
        den += w0;
    }

    const float r = 1.f / (den + 1e-16f);
    const float4 bv = *(const float4*)(bias + head * 64 + lane * 4);
    float4 v;
    v.x = (accA.x + accB.x + accC.x + accD.x) * r + bv.x;
    v.y = (accA.y + accB.y + accC.y + accD.y) * r + bv.y;
    v.z = (accA.z + accB.z + accC.z + accD.z) * r + bv.z;
    v.w = (accA.w + accB.w + accC.w + accD.w) * r + bv.w;
    v.x = v.x > 0.f ? v.x : 0.f;
    v.y = v.y > 0.f ? v.y : 0.f;
    v.z = v.z > 0.f ? v.z : 0.f;
    v.w = v.w > 0.f ? v.w : 0.f;
    *(float4*)(out + (size_t)node * 128 + head * 64 + lane * 4) = v;
}

// ---------------------------------------------------------------------------
// C: layer-3 gather (FP16 H3) + fused mean/bias/softmax. 8 lanes per node.
// ---------------------------------------------------------------------------
__global__ __launch_bounds__(256) void gat_gather_final(
    const int* __restrict__ rowptr, const int* __restrict__ esorted,
    const float* __restrict__ als, const float* __restrict__ ald,
    const __half* __restrict__ H3h, const float* __restrict__ b3,
    float* __restrict__ out, int N)
{
    const int node = blockIdx.x * 32 + ((int)threadIdx.x >> 3);
    const int lane = (int)threadIdx.x & 7;
    if (node >= N) return;
    const int head = lane >> 2;
    const int sub = lane & 3;

    const float* __restrict__ alsh = als + (size_t)head * N;
    const float aldh = ald[(size_t)head * N + node];
    const float ws = __expf(lrelu(alsh[node] + aldh));

    uint2 uo = *(const uint2*)(H3h + (size_t)node * 32 + head * 16 + sub * 4);
    float2 o01 = __half22float2(*reinterpret_cast<const __half2*>(&uo.x));
    float2 o23 = __half22float2(*reinterpret_cast<const __half2*>(&uo.y));
    float4 accA = make_float4(ws * o01.x, ws * o01.y, ws * o23.x, ws * o23.y);
    float4 accB = make_float4(0.f, 0.f, 0.f, 0.f);
    float den = ws;

    int p = rowptr[node];
    const int end = rowptr[node + 1];
    for (; p + 2 <= end; p += 2) {
        int s0 = esorted[p], s1 = esorted[p + 1];
        float l0 = alsh[s0], l1 = alsh[s1];
        uint2 u0 = *(const uint2*)(H3h + (size_t)s0 * 32 + head * 16 + sub * 4);
        uint2 u1 = *(const uint2*)(H3h + (size_t)s1 * 32 + head * 16 + sub * 4);
        float w0 = __expf(lrelu(l0 + aldh));
        float w1 = __expf(lrelu(l1 + aldh));
        float2 a01 = __half22float2(*reinterpret_cast<const __half2*>(&u0.x));
        float2 a23 = __half22float2(*reinterpret_cast<const __half2*>(&u0.y));
        float2 b01 = __half22float2(*reinterpret_cast<const __half2*>(&u1.x));
        float2 b23 = __half22float2(*reinterpret_cast<const __half2*>(&u1.y));
        accA.x = fmaf(w0, a01.x, accA.x); accA.y = fmaf(w0, a01.y, accA.y);
        accA.z = fmaf(w0, a23.x, accA.z); accA.w = fmaf(w0, a23.y, accA.w);
        accB.x = fmaf(w1, b01.x, accB.x); accB.y = fmaf(w1, b01.y, accB.y);
        accB.z = fmaf(w1, b23.x, accB.z); accB.w = fmaf(w1, b23.y, accB.w);
        den += w0 + w1;
    }
    if (p < end) {
        int s0 = esorted[p];
        float w0 = __expf(lrelu(alsh[s0] + aldh));
        uint2 u0 = *(const uint2*)(H3h + (size_t)s0 * 32 + head * 16 + sub * 4);
        float2 a01 = __half22float2(*reinterpret_cast<const __half2*>(&u0.x));
        float2 a23 = __half22float2(*reinterpret_cast<const __half2*>(&u0.y));
        accA.x = fmaf(w0, a01.x, accA.x); accA.y = fmaf(w0, a01.y, accA.y);
        accA.z = fmaf(w0, a23.x, accA.z); accA.w = fmaf(w0, a23.y, accA.w);
        den += w0;
    }

    const float r = 1.f / (den + 1e-16f);
    float4 a;
    a.x = (accA.x + accB.x) * r;
    a.y = (accA.y + accB.y) * r;
    a.z = (accA.z + accB.z) * r;
    a.w = (accA.w + accB.w) * r;
    float4 ap;
    ap.x = __shfl_xor(a.x, 4, 64);
    ap.y = __shfl_xor(a.y, 4, 64);
    ap.z = __shfl_xor(a.z, 4, 64);
    ap.w = __shfl_xor(a.w, 4, 64);
    const float4 bv = *(const float4*)(b3 + sub * 4);
    float4 v;
    v.x = 0.5f * (a.x + ap.x) + bv.x;
    v.y = 0.5f * (a.y + ap.y) + bv.y;
    v.z = 0.5f * (a.z + ap.z) + bv.z;
    v.w = 0.5f * (a.w + ap.w) + bv.w;
    float mx = fmaxf(fmaxf(v.x, v.y), fmaxf(v.z, v.w));
    mx = fmaxf(mx, __shfl_xor(mx, 1, 64));
    mx = fmaxf(mx, __shfl_xor(mx, 2, 64));
    float4 ex;
    ex.x = expf(v.x - mx);
    ex.y = expf(v.y - mx);
    ex.z = expf(v.z - mx);
    ex.w = expf(v.w - mx);
    float sum = ex.x + ex.y + ex.z + ex.w;
    sum += __shfl_xor(sum, 1, 64);
    sum += __shfl_xor(sum, 2, 64);
    const float rs = 1.f / sum;
    if (head == 0) {
        float4 o = make_float4(ex.x * rs, ex.y * rs, ex.z * rs, ex.w * rs);
        *(float4*)(out + (size_t)node * 16 + sub * 4) = o;
    }
}

// ---------------------------------------------------------------------------
extern "C" void kernel_launch(void* const* d_in, const int* in_sizes, int n_in,
                              void* d_out, int out_size, void* d_ws, size_t ws_size,
                              hipStream_t stream)
{
    const float* feat = (const float*)d_in[0];
    const int*   ei   = (const int*)d_in[1];
    const float* W1 = (const float*)d_in[2];
    const float* a1s = (const float*)d_in[3];
    const float* a1d = (const float*)d_in[4];
    const float* b1 = (const float*)d_in[5];
    const float* W2 = (const float*)d_in[6];
    const float* a2s = (const float*)d_in[7];
    const float* a2d = (const float*)d_in[8];
    const float* b2 = (const float*)d_in[9];
    const float* W3 = (const float*)d_in[10];
    const float* a3s = (const float*)d_in[11];
    const float* a3d = (const float*)d_in[12];
    const float* b3 = (const float*)d_in[13];

    const int N = in_sizes[0] / 64;
    const int E = in_sizes[1] / 2;
    const int* src = ei;
    const int* dst = ei + E;
    const int n2 = N * 2;
    const int nb = (N + SCAN_TILE - 1) / SCAN_TILE;

    // workspace layout (bufA = fp16 Hh for layers 1-2, fp16 H3 for layer 3)
    float* bufA  = (float*)d_ws;                    // N*128 floats
    float* bufB  = bufA + (size_t)N * 128;          // N*128 (x / out)
    float* als   = bufB + (size_t)N * 128;          // 2N head-major
    float* ald   = als + (size_t)n2;                // 2N head-major
    int* deg     = (int*)(ald + (size_t)n2);        // N
    int* rowptr  = deg + N;                         // N+1
    int* cursor  = rowptr + (N + 1);                // N
    int* bsum    = cursor + N;                      // nb
    int* esorted = bsum + nb;                       // E
    __half* HhA  = (__half*)bufA;                   // 2*N*64 halves (layers 1-2)
    __half* H3h  = (__half*)bufA;                   // N*32 halves (layer 3)

    dim3 blk(256);
    const int gE = (E + 255) / 256;
    const int nblk16 = (N + 15) / 16;
    const int gM = (N + 63) / 64;
    const int chunk = (N + 7) / 8;

    // --- build CSR by dst (once; shared by all 3 layers) ---
    k_zero_int<<<(N + 255) / 256, blk, 0, stream>>>(deg, N);
    k_hist<<<gE, blk, 0, stream>>>(dst, deg, E);
    k_scan1<<<nb, blk, 0, stream>>>(deg, bsum, N);
    k_scan3<<<nb, blk, 0, stream>>>(deg, bsum, rowptr, cursor, nb, N);
    k_scatter_xcd<<<8 * gE, blk, 0, stream>>>(src, dst, cursor, esorted, E, chunk);

    // --- layer 1 (K=64, OUT=128, MFMA fp16) ---
    gemm_mfma128<64><<<gM, blk, 0, stream>>>(feat, W1, a1s, a1d, HhA, als, ald, N);
    gat_gather_head<<<2 * nblk16, blk, 0, stream>>>(rowptr, esorted, als, ald, HhA, b1, bufB, N, nblk16);

    // --- layer 2 (K=128, OUT=128, MFMA fp16) ---
    gemm_mfma128<128><<<gM, blk, 0, stream>>>(bufB, W2, a2s, a2d, HhA, als, ald, N);
    gat_gather_head<<<2 * nblk16, blk, 0, stream>>>(rowptr, esorted, als, ald, HhA, b2, bufB, N, nblk16);

    // --- layer 3 (K=128, OUT=32, MFMA fp16, H3 fp16) ---
    gemm_mfma32<128><<<gM, blk, 0, stream>>>(bufB, W3, a3s, a3d, H3h, als, ald, N);
    gat_gather_final<<<(N + 31) / 32, blk, 0, stream>>>(rowptr, esorted, als, ald, H3h, b3, (float*)d_out, N);
}

// Round 17
// 232.550 us; speedup vs baseline: 1.4188x; 1.0089x over previous
//
#include <hip/hip_runtime.h>
#include <hip/hip_fp16.h>

#define NEG_SLOPE 0.2f

__device__ __forceinline__ float lrelu(float x) { return x > 0.f ? x : NEG_SLOPE * x; }

using half8 = __attribute__((ext_vector_type(8))) _Float16;
using f32x4 = __attribute__((ext_vector_type(4))) float;

// ---------------------------------------------------------------------------
// MFMA GEMM (layers 1-2): h = X @ W, OUT=128, fp16 inputs, fp32 accum.
// (unchanged from R16)
// ---------------------------------------------------------------------------
template<int K>
__global__ __launch_bounds__(256) void gemm_mfma128(
    const float* __restrict__ X, const float* __restrict__ W,
    const float* __restrict__ a_s, const float* __restrict__ a_d,
    __half* __restrict__ HoutH, float* __restrict__ als, float* __restrict__ ald,
    int n)
{
    constexpr int KP = K + 8;
    __shared__ __align__(16) _Float16 Xs[64 * KP];
    __shared__ __align__(16) _Float16 Wt[128 * KP];   // transposed: Wt[col][k]

    const int tid = (int)threadIdx.x;
    const int wid = tid >> 6;
    const int lane = tid & 63;
    const int r0 = blockIdx.x * 64;

    for (int i = tid; i < 64 * K / 4; i += 256) {
        int r = i / (K / 4);
        int kc = (i % (K / 4)) * 4;
        int gr = r0 + r;
        float4 v = make_float4(0.f, 0.f, 0.f, 0.f);
        if (gr < n) v = *(const float4*)(X + (size_t)gr * K + kc);
        _Float16* d = &Xs[r * KP + kc];
        d[0] = (_Float16)v.x; d[1] = (_Float16)v.y;
        d[2] = (_Float16)v.z; d[3] = (_Float16)v.w;
    }
    for (int i = tid; i < K * 128 / 4; i += 256) {
        int k = i / 32;
        int c = (i % 32) * 4;
        float4 v = *(const float4*)(W + (size_t)k * 128 + c);
        Wt[(c + 0) * KP + k] = (_Float16)v.x;
        Wt[(c + 1) * KP + k] = (_Float16)v.y;
        Wt[(c + 2) * KP + k] = (_Float16)v.z;
        Wt[(c + 3) * KP + k] = (_Float16)v.w;
    }
    __syncthreads();

    const int arow = wid * 16 + (lane & 15);
    const int kg = (lane >> 4) * 8;

    f32x4 acc[8];
#pragma unroll
    for (int ct = 0; ct < 8; ++ct) acc[ct] = (f32x4){0.f, 0.f, 0.f, 0.f};

#pragma unroll
    for (int k0 = 0; k0 < K; k0 += 32) {
        half8 a = *(const half8*)&Xs[arow * KP + k0 + kg];
#pragma unroll
        for (int ct = 0; ct < 8; ++ct) {
            half8 b = *(const half8*)&Wt[(ct * 16 + (lane & 15)) * KP + k0 + kg];
            acc[ct] = __builtin_amdgcn_mfma_f32_16x16x32_f16(a, b, acc[ct], 0, 0, 0);
        }
    }

    const int ccol = lane & 15;
    float asl[8], adl[8];
#pragma unroll
    for (int ct = 0; ct < 8; ++ct) {
        asl[ct] = a_s[ct * 16 + ccol];
        adl[ct] = a_d[ct * 16 + ccol];
    }
    const int crow = wid * 16 + (lane >> 4) * 4;

#pragma unroll
    for (int j = 0; j < 4; ++j) {
        int gr = r0 + crow + j;
        float ps0 = 0.f, pd0 = 0.f, ps1 = 0.f, pd1 = 0.f;
#pragma unroll
        for (int ct = 0; ct < 8; ++ct) {
            float h = acc[ct][j];
            if (ct < 4) { ps0 = fmaf(h, asl[ct], ps0); pd0 = fmaf(h, adl[ct], pd0); }
            else        { ps1 = fmaf(h, asl[ct], ps1); pd1 = fmaf(h, adl[ct], pd1); }
        }
#pragma unroll
        for (int off = 1; off < 16; off <<= 1) {
            ps0 += __shfl_xor(ps0, off, 64);
            pd0 += __shfl_xor(pd0, off, 64);
            ps1 += __shfl_xor(ps1, off, 64);
            pd1 += __shfl_xor(pd1, off, 64);
        }
        if (gr < n) {
            if (ccol == 0) {
                als[gr] = ps0;              ald[gr] = pd0;
                als[(size_t)n + gr] = ps1;  ald[(size_t)n + gr] = pd1;
            }
#pragma unroll
            for (int ct = 0; ct < 8; ++ct) {
                int col = ct * 16 + ccol;
                HoutH[((size_t)(col >> 6) * n + gr) * 64 + (col & 63)] =
                    __float2half_rn(acc[ct][j]);
            }
        }
    }
}

// ---------------------------------------------------------------------------
// MFMA GEMM (layer 3): OUT=32, H3 fp16 (unchanged from R16).
// ---------------------------------------------------------------------------
template<int K>
__global__ __launch_bounds__(256) void gemm_mfma32(
    const float* __restrict__ X, const float* __restrict__ W,
    const float* __restrict__ a_s, const float* __restrict__ a_d,
    __half* __restrict__ H3h, float* __restrict__ als, float* __restrict__ ald,
    int n)
{
    constexpr int KP = K + 8;
    __shared__ __align__(16) _Float16 Xs[64 * KP];
    __shared__ __align__(16) _Float16 Wt[32 * KP];

    const int tid = (int)threadIdx.x;
    const int wid = tid >> 6;
    const int lane = tid & 63;
    const int r0 = blockIdx.x * 64;

    for (int i = tid; i < 64 * K / 4; i += 256) {
        int r = i / (K / 4);
        int kc = (i % (K / 4)) * 4;
        int gr = r0 + r;
        float4 v = make_float4(0.f, 0.f, 0.f, 0.f);
        if (gr < n) v = *(const float4*)(X + (size_t)gr * K + kc);
        _Float16* d = &Xs[r * KP + kc];
        d[0] = (_Float16)v.x; d[1] = (_Float16)v.y;
        d[2] = (_Float16)v.z; d[3] = (_Float16)v.w;
    }
    for (int i = tid; i < K * 32 / 4; i += 256) {
        int k = i / 8;
        int c = (i % 8) * 4;
        float4 v = *(const float4*)(W + (size_t)k * 32 + c);
        Wt[(c + 0) * KP + k] = (_Float16)v.x;
        Wt[(c + 1) * KP + k] = (_Float16)v.y;
        Wt[(c + 2) * KP + k] = (_Float16)v.z;
        Wt[(c + 3) * KP + k] = (_Float16)v.w;
    }
    __syncthreads();

    const int arow = wid * 16 + (lane & 15);
    const int kg = (lane >> 4) * 8;

    f32x4 acc[2];
    acc[0] = (f32x4){0.f, 0.f, 0.f, 0.f};
    acc[1] = (f32x4){0.f, 0.f, 0.f, 0.f};

#pragma unroll
    for (int k0 = 0; k0 < K; k0 += 32) {
        half8 a = *(const half8*)&Xs[arow * KP + k0 + kg];
#pragma unroll
        for (int ct = 0; ct < 2; ++ct) {
            half8 b = *(const half8*)&Wt[(ct * 16 + (lane & 15)) * KP + k0 + kg];
            acc[ct] = __builtin_amdgcn_mfma_f32_16x16x32_f16(a, b, acc[ct], 0, 0, 0);
        }
    }

    const int ccol = lane & 15;
    const float as0 = a_s[ccol], as1 = a_s[16 + ccol];
    const float ad0 = a_d[ccol], ad1 = a_d[16 + ccol];
    const int crow = wid * 16 + (lane >> 4) * 4;

#pragma unroll
    for (int j = 0; j < 4; ++j) {
        int gr = r0 + crow + j;
        float ps0 = acc[0][j] * as0, pd0 = acc[0][j] * ad0;
        float ps1 = acc[1][j] * as1, pd1 = acc[1][j] * ad1;
#pragma unroll
        for (int off = 1; off < 16; off <<= 1) {
            ps0 += __shfl_xor(ps0, off, 64);
            pd0 += __shfl_xor(pd0, off, 64);
            ps1 += __shfl_xor(ps1, off, 64);
            pd1 += __shfl_xor(pd1, off, 64);
        }
        if (gr < n) {
            if (ccol == 0) {
                als[gr] = ps0;              ald[gr] = pd0;
                als[(size_t)n + gr] = ps1;  ald[(size_t)n + gr] = pd1;
            }
            H3h[(size_t)gr * 32 + ccol]      = __float2half_rn(acc[0][j]);
            H3h[(size_t)gr * 32 + 16 + ccol] = __float2half_rn(acc[1][j]);
        }
    }
}

// ---------------------------------------------------------------------------
// CSR build (unchanged from R16).
// ---------------------------------------------------------------------------
#define SCAN_TILE 1024

__global__ __launch_bounds__(256) void k_zero_int(int* __restrict__ p, int n) {
    int i = blockIdx.x * 256 + threadIdx.x;
    if (i < n) p[i] = 0;
}

__global__ __launch_bounds__(256) void k_hist(const int* __restrict__ dst,
                                              int* __restrict__ deg, int E) {
    int e = blockIdx.x * 256 + threadIdx.x;
    if (e < E) atomicAdd(&deg[dst[e]], 1);
}

__global__ __launch_bounds__(256) void k_scan1(const int* __restrict__ deg,
                                               int* __restrict__ bsum, int N) {
    __shared__ int sm[256];
    int base = blockIdx.x * SCAN_TILE;
    int t = threadIdx.x;
    int s = 0;
#pragma unroll
    for (int j = 0; j < SCAN_TILE / 256; ++j) {
        int i = base + j * 256 + t;
        if (i < N) s += deg[i];
    }
    sm[t] = s;
    __syncthreads();
    for (int off = 128; off > 0; off >>= 1) {
        if (t < off) sm[t] += sm[t + off];
        __syncthreads();
    }
    if (t == 0) bsum[blockIdx.x] = sm[0];
}

__global__ __launch_bounds__(256) void k_scan3(const int* __restrict__ deg,
                                               const int* __restrict__ bsum,
                                               int* __restrict__ rowptr,
                                               int* __restrict__ cursor,
                                               int nb, int N) {
    __shared__ int sm[256];
    __shared__ int sme[256];
    int t = threadIdx.x;
    int v = (t < nb) ? bsum[t] : 0;
    sm[t] = v;
    __syncthreads();
    for (int off = 1; off < 256; off <<= 1) {
        int u = (t >= off) ? sm[t - off] : 0;
        __syncthreads();
        sm[t] += u;
        __syncthreads();
    }
    sme[t] = sm[t] - v;
    if (blockIdx.x == 0 && t == 255) rowptr[N] = sm[255];
    __syncthreads();
    const int boffv = sme[blockIdx.x];

    int base = blockIdx.x * SCAN_TILE;
    int i0 = base + t * 4;
    int d0 = 0, d1 = 0, d2 = 0, d3 = 0;
    if (i0 + 3 < N) {
        int4 dv = *(const int4*)(deg + i0);
        d0 = dv.x; d1 = dv.y; d2 = dv.z; d3 = dv.w;
    } else {
        if (i0 + 0 < N) d0 = deg[i0 + 0];
        if (i0 + 1 < N) d1 = deg[i0 + 1];
        if (i0 + 2 < N) d2 = deg[i0 + 2];
        if (i0 + 3 < N) d3 = deg[i0 + 3];
    }
    int tsum = d0 + d1 + d2 + d3;
    __syncthreads();
    sm[t] = tsum;
    __syncthreads();
    for (int off = 1; off < 256; off <<= 1) {
        int u = (t >= off) ? sm[t - off] : 0;
        __syncthreads();
        sm[t] += u;
        __syncthreads();
    }
    int run = boffv + sm[t] - tsum;
    if (i0 + 0 < N) { rowptr[i0 + 0] = run; cursor[i0 + 0] = run; run += d0; }
    if (i0 + 1 < N) { rowptr[i0 + 1] = run; cursor[i0 + 1] = run; run += d1; }
    if (i0 + 2 < N) { rowptr[i0 + 2] = run; cursor[i0 + 2] = run; run += d2; }
    if (i0 + 3 < N) { rowptr[i0 + 3] = run; cursor[i0 + 3] = run; run += d3; }
}

__global__ __launch_bounds__(256) void k_scatter_xcd(
    const int* __restrict__ src, const int* __restrict__ dst,
    int* __restrict__ cursor, int* __restrict__ esorted, int E, int chunk) {
    const int slice = blockIdx.x & 7;
    const int lo = slice * chunk;
    const int hi = lo + chunk;
    int e = (blockIdx.x >> 3) * 256 + threadIdx.x;
    if (e >= E) return;
    int d = dst[e];
    if (d < lo || d >= hi) return;
    int p = atomicAdd(&cursor[d], 1);
    esorted[p] = src[e];
}

// ---------------------------------------------------------------------------
// B: head-phased gather, FP16 H, 8 LANES per (node,head), uint4 = 8 halves
// per lane. Overhead ops (esorted/als/exp/den/loop) now amortize over 8
// node-streams per wave instead of 4 -> fewer wave-instructions per edge.
// 2-edge unroll keeps 2 row-loads in flight per stream.
// ---------------------------------------------------------------------------
__global__ __launch_bounds__(256) void gat_gather_head(
    const int* __restrict__ rowptr, const int* __restrict__ esorted,
    const float* __restrict__ als, const float* __restrict__ ald,
    const __half* __restrict__ Hh, const float* __restrict__ bias,
    float* __restrict__ out, int N, int nblk)
{
    const int head = (blockIdx.x >= nblk) ? 1 : 0;
    const int nodeblk = blockIdx.x - head * nblk;
    const int node = nodeblk * 32 + ((int)threadIdx.x >> 3);
    const int lane = (int)threadIdx.x & 7;            // 8 lanes x 8 halves
    if (node >= N) return;

    const float* __restrict__ alsh = als + (size_t)head * N;
    const float aldh = ald[(size_t)head * N + node];
    const __half* __restrict__ Ht = Hh + (size_t)head * N * 64;

    const float ws = __expf(lrelu(alsh[node] + aldh));

    uint4 uo = *(const uint4*)(Ht + (size_t)node * 64 + lane * 8);
    float2 o0 = __half22float2(*reinterpret_cast<const __half2*>(&uo.x));
    float2 o1 = __half22float2(*reinterpret_cast<const __half2*>(&uo.y));
    float2 o2 = __half22float2(*reinterpret_cast<const __half2*>(&uo.z));
    float2 o3 = __half22float2(*reinterpret_cast<const __half2*>(&uo.w));
    float4 aLo = make_float4(ws * o0.x, ws * o0.y, ws * o1.x, ws * o1.y);
    float4 aHi = make_float4(ws * o2.x, ws * o2.y, ws * o3.x, ws * o3.y);
    float4 bLo = make_float4(0.f, 0.f, 0.f, 0.f);
    float4 bHi = make_float4(0.f, 0.f, 0.f, 0.f);
    float den = ws;

    int p = rowptr[node];
    const int end = rowptr[node + 1];
    for (; p + 2 <= end; p += 2) {
        int s0 = esorted[p], s1 = esorted[p + 1];
        float l0 = alsh[s0], l1 = alsh[s1];
        uint4 u0 = *(const uint4*)(Ht + (size_t)s0 * 64 + lane * 8);
        uint4 u1 = *(const uint4*)(Ht + (size_t)s1 * 64 + lane * 8);
        float w0 = __expf(lrelu(l0 + aldh));
        float w1 = __expf(lrelu(l1 + aldh));
        float2 p0 = __half22float2(*reinterpret_cast<const __half2*>(&u0.x));
        float2 p1 = __half22float2(*reinterpret_cast<const __half2*>(&u0.y));
        float2 p2 = __half22float2(*reinterpret_cast<const __half2*>(&u0.z));
        float2 p3 = __half22float2(*reinterpret_cast<const __half2*>(&u0.w));
        float2 q0 = __half22float2(*reinterpret_cast<const __half2*>(&u1.x));
        float2 q1 = __half22float2(*reinterpret_cast<const __half2*>(&u1.y));
        float2 q2 = __half22float2(*reinterpret_cast<const __half2*>(&u1.z));
        float2 q3 = __half22float2(*reinterpret_cast<const __half2*>(&u1.w));
        aLo.x = fmaf(w0, p0.x, aLo.x); aLo.y = fmaf(w0, p0.y, aLo.y);
        aLo.z = fmaf(w0, p1.x, aLo.z); aLo.w = fmaf(w0, p1.y, aLo.w);
        aHi.x = fmaf(w0, p2.x, aHi.x); aHi.y = fmaf(w0, p2.y, aHi.y);
        aHi.z = fmaf(w0, p3.x, aHi.z); aHi.w = fmaf(w0, p3.y, aHi.w);
        bLo.x = fmaf(w1, q0.x, bLo.x); bLo.y = fmaf(w1, q0.y, bLo.y);
        bLo.z = fmaf(w1, q1.x, bLo.z); bLo.w = fmaf(w1, q1.y, bLo.w);
        bHi.x = fmaf(w1, q2.x, bHi.x); bHi.y = fmaf(w1, q2.y, bHi.y);
        bHi.z = fmaf(w1, q3.x, bHi.z); bHi.w = fmaf(w1, q3.y, bHi.w);
        den += w0 + w1;
    }
    if (p < end) {
        int s0 = esorted[p];
        float w0 = __expf(lrelu(alsh[s0] + aldh));
        uint4 u0 = *(const uint4*)(Ht + (size_t)s0 * 64 + lane * 8);
        float2 p0 = __half22float2(*reinterpret_cast<const __half2*>(&u0.x));
        float2 p1 = __half22float2(*reinterpret_cast<const __half2*>(&u0.y));
        float2 p2 = __half22float2(*reinterpret_cast<const __half2*>(&u0.z));
        float2 p3 = __half22float2(*reinterpret_cast<const __half2*>(&u0.w));
        aLo.x = fmaf(w0, p0.x, aLo.x); aLo.y = fmaf(w0, p0.y, aLo.y);
        aLo.z = fmaf(w0, p1.x, aLo.z); aLo.w = fmaf(w0, p1.y, aLo.w);
        aHi.x = fmaf(w0, p2.x, aHi.x); aHi.y = fmaf(w0, p2.y, aHi.y);
        aHi.z = fmaf(w0, p3.x, aHi.z); aHi.w = fmaf(w0, p3.y, aHi.w);
        den += w0;
    }

    const float r = 1.f / (den + 1e-16f);
    float* outp = out + (size_t)node * 128 + head * 64 + lane * 8;
    const float* bp = bias + head * 64 + lane * 8;
    float4 b0 = *(const float4*)bp;
    float4 b1 = *(const float4*)(bp + 4);
    float4 v0, v1;
    v0.x = (aLo.x + bLo.x) * r + b0.x;
    v0.y = (aLo.y + bLo.y) * r + b0.y;
    v0.z = (aLo.z + bLo.z) * r + b0.z;
    v0.w = (aLo.w + bLo.w) * r + b0.w;
    v1.x = (aHi.x + bHi.x) * r + b1.x;
    v1.y = (aHi.y + bHi.y) * r + b1.y;
    v1.z = (aHi.z + bHi.z) * r + b1.z;
    v1.w = (aHi.w + bHi.w) * r + b1.w;
    v0.x = v0.x > 0.f ? v0.x : 0.f;
    v0.y = v0.y > 0.f ? v0.y : 0.f;
    v0.z = v0.z > 0.f ? v0.z : 0.f;
    v0.w = v0.w > 0.f ? v0.w : 0.f;
    v1.x = v1.x > 0.f ? v1.x : 0.f;
    v1.y = v1.y > 0.f ? v1.y : 0.f;
    v1.z = v1.z > 0.f ? v1.z : 0.f;
    v1.w = v1.w > 0.f ? v1.w : 0.f;
    *(float4*)outp = v0;
    *(float4*)(outp + 4) = v1;
}

// ---------------------------------------------------------------------------
// C: layer-3 gather (FP16 H3) + fused mean/bias/softmax (unchanged from R16).
// ---------------------------------------------------------------------------
__global__ __launch_bounds__(256) void gat_gather_final(
    const int* __restrict__ rowptr, const int* __restrict__ esorted,
    const float* __restrict__ als, const float* __restrict__ ald,
    const __half* __restrict__ H3h, const float* __restrict__ b3,
    float* __restrict__ out, int N)
{
    const int node = blockIdx.x * 32 + ((int)threadIdx.x >> 3);
    const int lane = (int)threadIdx.x & 7;
    if (node >= N) return;
    const int head = lane >> 2;
    const int sub = lane & 3;

    const float* __restrict__ alsh = als + (size_t)head * N;
    const float aldh = ald[(size_t)head * N + node];
    const float ws = __expf(lrelu(alsh[node] + aldh));

    uint2 uo = *(const uint2*)(H3h + (size_t)node * 32 + head * 16 + sub * 4);
    float2 o01 = __half22float2(*reinterpret_cast<const __half2*>(&uo.x));
    float2 o23 = __half22float2(*reinterpret_cast<const __half2*>(&uo.y));
    float4 accA = make_float4(ws * o01.x, ws * o01.y, ws * o23.x, ws * o23.y);
    float4 accB = make_float4(0.f, 0.f, 0.f, 0.f);
    float den = ws;

    int p = rowptr[node];
    const int end = rowptr[node + 1];
    for (; p + 2 <= end; p += 2) {
        int s0 = esorted[p], s1 = esorted[p + 1];
        float l0 = alsh[s0], l1 = alsh[s1];
        uint2 u0 = *(const uint2*)(H3h + (size_t)s0 * 32 + head * 16 + sub * 4);
        uint2 u1 = *(const uint2*)(H3h + (size_t)s1 * 32 + head * 16 + sub * 4);
        float w0 = __expf(lrelu(l0 + aldh));
        float w1 = __expf(lrelu(l1 + aldh));
        float2 a01 = __half22float2(*reinterpret_cast<const __half2*>(&u0.x));
        float2 a23 = __half22float2(*reinterpret_cast<const __half2*>(&u0.y));
        float2 b01 = __half22float2(*reinterpret_cast<const __half2*>(&u1.x));
        float2 b23 = __half22float2(*reinterpret_cast<const __half2*>(&u1.y));
        accA.x = fmaf(w0, a01.x, accA.x); accA.y = fmaf(w0, a01.y, accA.y);
        accA.z = fmaf(w0, a23.x, accA.z); accA.w = fmaf(w0, a23.y, accA.w);
        accB.x = fmaf(w1, b01.x, accB.x); accB.y = fmaf(w1, b01.y, accB.y);
        accB.z = fmaf(w1, b23.x, accB.z); accB.w = fmaf(w1, b23.y, accB.w);
        den += w0 + w1;
    }
    if (p < end) {
        int s0 = esorted[p];
        float w0 = __expf(lrelu(alsh[s0] + aldh));
        uint2 u0 = *(const uint2*)(H3h + (size_t)s0 * 32 + head * 16 + sub * 4);
        float2 a01 = __half22float2(*reinterpret_cast<const __half2*>(&u0.x));
        float2 a23 = __half22float2(*reinterpret_cast<const __half2*>(&u0.y));
        accA.x = fmaf(w0, a01.x, accA.x); accA.y = fmaf(w0, a01.y, accA.y);
        accA.z = fmaf(w0, a23.x, accA.z); accA.w = fmaf(w0, a23.y, accA.w);
        den += w0;
    }

    const float r = 1.f / (den + 1e-16f);
    float4 a;
    a.x = (accA.x + accB.x) * r;
    a.y = (accA.y + accB.y) * r;
    a.z = (accA.z + accB.z) * r;
    a.w = (accA.w + accB.w) * r;
    float4 ap;
    ap.x = __shfl_xor(a.x, 4, 64);
    ap.y = __shfl_xor(a.y, 4, 64);
    ap.z = __shfl_xor(a.z, 4, 64);
    ap.w = __shfl_xor(a.w, 4, 64);
    const float4 bv = *(const float4*)(b3 + sub * 4);
    float4 v;
    v.x = 0.5f * (a.x + ap.x) + bv.x;
    v.y = 0.5f * (a.y + ap.y) + bv.y;
    v.z = 0.5f * (a.z + ap.z) + bv.z;
    v.w = 0.5f * (a.w + ap.w) + bv.w;
    float mx = fmaxf(fmaxf(v.x, v.y), fmaxf(v.z, v.w));
    mx = fmaxf(mx, __shfl_xor(mx, 1, 64));
    mx = fmaxf(mx, __shfl_xor(mx, 2, 64));
    float4 ex;
    ex.x = expf(v.x - mx);
    ex.y = expf(v.y - mx);
    ex.z = expf(v.z - mx);
    ex.w = expf(v.w - mx);
    float sum = ex.x + ex.y + ex.z + ex.w;
    sum += __shfl_xor(sum, 1, 64);
    sum += __shfl_xor(sum, 2, 64);
    const float rs = 1.f / sum;
    if (head == 0) {
        float4 o = make_float4(ex.x * rs, ex.y * rs, ex.z * rs, ex.w * rs);
        *(float4*)(out + (size_t)node * 16 + sub * 4) = o;
    }
}

// ---------------------------------------------------------------------------
extern "C" void kernel_launch(void* const* d_in, const int* in_sizes, int n_in,
                              void* d_out, int out_size, void* d_ws, size_t ws_size,
                              hipStream_t stream)
{
    const float* feat = (const float*)d_in[0];
    const int*   ei   = (const int*)d_in[1];
    const float* W1 = (const float*)d_in[2];
    const float* a1s = (const float*)d_in[3];
    const float* a1d = (const float*)d_in[4];
    const float* b1 = (const float*)d_in[5];
    const float* W2 = (const float*)d_in[6];
    const float* a2s = (const float*)d_in[7];
    const float* a2d = (const float*)d_in[8];
    const float* b2 = (const float*)d_in[9];
    const float* W3 = (const float*)d_in[10];
    const float* a3s = (const float*)d_in[11];
    const float* a3d = (const float*)d_in[12];
    const float* b3 = (const float*)d_in[13];

    const int N = in_sizes[0] / 64;
    const int E = in_sizes[1] / 2;
    const int* src = ei;
    const int* dst = ei + E;
    const int n2 = N * 2;
    const int nb = (N + SCAN_TILE - 1) / SCAN_TILE;

    // workspace layout (bufA = fp16 Hh for layers 1-2, fp16 H3 for layer 3)
    float* bufA  = (float*)d_ws;                    // N*128 floats
    float* bufB  = bufA + (size_t)N * 128;          // N*128 (x / out)
    float* als   = bufB + (size_t)N * 128;          // 2N head-major
    float* ald   = als + (size_t)n2;                // 2N head-major
    int* deg     = (int*)(ald + (size_t)n2);        // N
    int* rowptr  = deg + N;                         // N+1
    int* cursor  = rowptr + (N + 1);                // N
    int* bsum    = cursor + N;                      // nb
    int* esorted = bsum + nb;                       // E
    __half* HhA  = (__half*)bufA;                   // 2*N*64 halves (layers 1-2)
    __half* H3h  = (__half*)bufA;                   // N*32 halves (layer 3)

    dim3 blk(256);
    const int gE = (E + 255) / 256;
    const int nblk32 = (N + 31) / 32;
    const int gM = (N + 63) / 64;
    const int chunk = (N + 7) / 8;

    // --- build CSR by dst (once; shared by all 3 layers) ---
    k_zero_int<<<(N + 255) / 256, blk, 0, stream>>>(deg, N);
    k_hist<<<gE, blk, 0, stream>>>(dst, deg, E);
    k_scan1<<<nb, blk, 0, stream>>>(deg, bsum, N);
    k_scan3<<<nb, blk, 0, stream>>>(deg, bsum, rowptr, cursor, nb, N);
    k_scatter_xcd<<<8 * gE, blk, 0, stream>>>(src, dst, cursor, esorted, E, chunk);

    // --- layer 1 (K=64, OUT=128, MFMA fp16) ---
    gemm_mfma128<64><<<gM, blk, 0, stream>>>(feat, W1, a1s, a1d, HhA, als, ald, N);
    gat_gather_head<<<2 * nblk32, blk, 0, stream>>>(rowptr, esorted, als, ald, HhA, b1, bufB, N, nblk32);

    // --- layer 2 (K=128, OUT=128, MFMA fp16) ---
    gemm_mfma128<128><<<gM, blk, 0, stream>>>(bufB, W2, a2s, a2d, HhA, als, ald, N);
    gat_gather_head<<<2 * nblk32, blk, 0, stream>>>(rowptr, esorted, als, ald, HhA, b2, bufB, N, nblk32);

    // --- layer 3 (K=128, OUT=32, MFMA fp16, H3 fp16) ---
    gemm_mfma32<128><<<gM, blk, 0, stream>>>(bufB, W3, a3s, a3d, H3h, als, ald, N);
    gat_gather_final<<<(N + 31) / 32, blk, 0, stream>>>(rowptr, esorted, als, ald, H3h, b3, (float*)d_out, N);
}